// Round 7
// baseline (710.642 us; speedup 1.0000x reference)
//
#include <hip/hip_runtime.h>

#define N_NODES 50000
#define N_EDGES 800000
#define DD 128
#define GG 256
#define LL 4
#define EPSV 1e-5f
#define NB 196  // ceil(N_NODES/256)
#define AGGQ_BLOCKS 2048  // 8 blocks/CU; quarter q = (blockIdx%8)>>1 -> XCD pair pinning
#define GEMM_BLOCKS 782   // ceil(N/64)

typedef __attribute__((ext_vector_type(8))) short s16x8;    // 8 bf16 (4 VGPRs)
typedef __attribute__((ext_vector_type(4))) float f32x4;    // 4 fp32 acc

// ---------------- bf16 helpers ----------------
static __device__ __forceinline__ unsigned bf16pack(float a, float b) {
    unsigned ua = __float_as_uint(a), ub = __float_as_uint(b);
    ua = (ua + 0x7FFFu + ((ua >> 16) & 1u)) >> 16;  // RNE
    ub = (ub + 0x7FFFu + ((ub >> 16) & 1u)) >> 16;
    return ua | (ub << 16);
}
static __device__ __forceinline__ unsigned short bf16r(float a) {
    unsigned u = __float_as_uint(a);
    u = (u + 0x7FFFu + ((u >> 16) & 1u)) >> 16;
    return (unsigned short)u;
}
static __device__ __forceinline__ float2 bf16unpack(unsigned u) {
    float2 r;
    r.x = __uint_as_float(u << 16);
    r.y = __uint_as_float(u & 0xFFFF0000u);
    return r;
}

// ---------------- setup kernels ----------------

__global__ void count_deg_kernel(const int* __restrict__ ei, const float* __restrict__ w,
                                 float* __restrict__ cd) {
    int e = blockIdx.x * 256 + threadIdx.x;
    if (e < N_EDGES) {
        int d = ei[N_EDGES + e];
        atomicAdd(&((int*)cd)[2 * d], 1);
        atomicAdd(&cd[2 * d + 1], w[e]);
    }
}

__global__ void dinv_kernel(const float* __restrict__ cd, float* __restrict__ dinv) {
    int i = blockIdx.x * 256 + threadIdx.x;
    if (i < N_NODES) {
        float d = cd[2 * i + 1] + 2.0f;  // self-loop weight 2.0
        dinv[i] = rsqrtf(fmaxf(d, EPSV));
    }
}

__global__ __launch_bounds__(256) void blocksum_kernel(const float* __restrict__ cd,
                                                       int* __restrict__ bsums) {
    int i = blockIdx.x * 256 + threadIdx.x;
    int v = (i < N_NODES) ? ((const int*)cd)[2 * i] : 0;
    for (int off = 32; off; off >>= 1) v += __shfl_down(v, off);
    __shared__ int s[4];
    if ((threadIdx.x & 63) == 0) s[threadIdx.x >> 6] = v;
    __syncthreads();
    if (threadIdx.x == 0) bsums[blockIdx.x] = s[0] + s[1] + s[2] + s[3];
}

__global__ __launch_bounds__(256) void scan_bsums_kernel(const int* __restrict__ bsums,
                                                         int* __restrict__ boffs,
                                                         int* __restrict__ rowptr) {
    __shared__ int s[256];
    int t = threadIdx.x;
    int v = (t < NB) ? bsums[t] : 0;
    s[t] = v;
    __syncthreads();
    for (int off = 1; off < 256; off <<= 1) {
        int u = (t >= off) ? s[t - off] : 0;
        __syncthreads();
        s[t] += u;
        __syncthreads();
    }
    if (t < NB) boffs[t] = s[t] - v;  // exclusive
    if (t == 0) rowptr[N_NODES] = N_EDGES;
}

__global__ __launch_bounds__(256) void rowptr_kernel(const float* __restrict__ cd,
                                                     const int* __restrict__ boffs,
                                                     int* __restrict__ rowptr,
                                                     int* __restrict__ cursor) {
    __shared__ int s[256];
    int i = blockIdx.x * 256 + threadIdx.x;
    int t = threadIdx.x;
    int c = (i < N_NODES) ? ((const int*)cd)[2 * i] : 0;
    s[t] = c;
    __syncthreads();
    for (int off = 1; off < 256; off <<= 1) {
        int u = (t >= off) ? s[t - off] : 0;
        __syncthreads();
        s[t] += u;
        __syncthreads();
    }
    if (i < N_NODES) {
        int r = boffs[blockIdx.x] + s[t] - c;
        rowptr[i] = r;
        cursor[i] = r;
    }
}

__global__ void fill_kernel(const int* __restrict__ ei, const float* __restrict__ w,
                            const float* __restrict__ dinv, int* __restrict__ cursor,
                            uint2* __restrict__ edat) {
    int e = blockIdx.x * 256 + threadIdx.x;
    if (e < N_EDGES) {
        int s_ = ei[e];
        int d = ei[N_EDGES + e];
        int pos = atomicAdd(&cursor[d], 1);
        edat[pos] = make_uint2((unsigned)s_, __float_as_uint(dinv[s_] * w[e] * dinv[d]));
    }
}

// ---------------- weight prep: fp32 W[k][n] -> fragment-ordered bf16 ----------------
__global__ void wprep_kernel(const float* __restrict__ preW, const float* __restrict__ convW,
                             unsigned short* __restrict__ Wf) {
    int idx = blockIdx.x * 256 + threadIdx.x;  // 5*16384
    if (idx >= 5 * 16384) return;
    int l = idx >> 14, kn = idx & 16383;
    int k = kn >> 7, nn = kn & 127;
    float v = (l == 0) ? preW[kn] : convW[(l - 1) * 16384 + kn];
    int nt = nn >> 4, nl = nn & 15, kc = k >> 5, q = (k >> 3) & 3, j = k & 7;
    Wf[(size_t)l * 16384 + ((((nt * 4 + kc) * 4 + q) * 16 + nl) * 8 + j)] = bf16r(v);
}

// ---------------- MFMA GEMM: out[n,128] = act(A)[n,128] @ W[128,128] ----------------
// OUTBF16 writes QUARTER-MAJOR packed bf16: hQ[q][row][16 uints], q = col>>5.
template <bool AFFINE, bool STATS, bool OUTBF16>
__global__ __launch_bounds__(256) void gemm_mfma(const float* __restrict__ A, int n,
                                                 const uint4* __restrict__ Wf,
                                                 const float* __restrict__ stats_in,
                                                 const float* __restrict__ bn_sc,
                                                 const float* __restrict__ bn_bi,
                                                 const float* __restrict__ bias,
                                                 void* __restrict__ outv,
                                                 float* __restrict__ stats_out) {
    __shared__ unsigned short Af[8192];  // A frags
    __shared__ float WC[8448];           // W frags then C tile 64x132
    __shared__ float affg[128], affb[128];
    int t = threadIdx.x;
    int row0 = blockIdx.x * 64;

    if (AFFINE) {
        if (t < 128) {
            float mean = stats_in[t] * (1.0f / N_NODES);
            float var = fmaxf(stats_in[128 + t] * (1.0f / N_NODES) - mean * mean, 0.f);
            float g = bn_sc[t] * rsqrtf(var + EPSV);
            affg[t] = g;
            affb[t] = bn_bi[t] - mean * g;
        }
        __syncthreads();
    }
    {  // stage W fragments
        uint4* Wl = (uint4*)WC;
#pragma unroll
        for (int it = 0; it < 8; ++it) Wl[t + it * 256] = Wf[t + it * 256];
    }
    {  // stage A into fragment order (bf16), affine+relu fused
#pragma unroll
        for (int it = 0; it < 8; ++it) {
            int f = t * 4 + it * 1024;
            int r = f >> 7, c = f & 127;
            int row = row0 + r;
            float4 v = make_float4(0.f, 0.f, 0.f, 0.f);
            if (row < n) v = *(const float4*)&A[(size_t)row * 128 + c];
            if (AFFINE) {
                float4 g = *(float4*)&affg[c];
                float4 bb = *(float4*)&affb[c];
                v.x = fmaxf(v.x * g.x + bb.x, 0.f);
                v.y = fmaxf(v.y * g.y + bb.y, 0.f);
                v.z = fmaxf(v.z * g.z + bb.z, 0.f);
                v.w = fmaxf(v.w * g.w + bb.w, 0.f);
            }
            int w = r >> 4, mrow = r & 15, kc = c >> 5, q = (c >> 3) & 3, jo = c & 7;
            unsigned short* dst = &Af[(((w * 4 + kc) * 4 + q) * 16 + mrow) * 8 + jo];
            *(uint2*)dst = make_uint2(bf16pack(v.x, v.y), bf16pack(v.z, v.w));
        }
    }
    __syncthreads();

    int wv = t >> 6, lane = t & 63, q = lane >> 4, ml = lane & 15;
    f32x4 acc[8];
#pragma unroll
    for (int nt = 0; nt < 8; nt++) acc[nt] = (f32x4){0.f, 0.f, 0.f, 0.f};
    const unsigned short* Wb = (const unsigned short*)WC;
#pragma unroll
    for (int kc = 0; kc < 4; kc++) {
        s16x8 a = *(const s16x8*)&Af[(((wv * 4 + kc) * 4 + q) * 16 + ml) * 8];
#pragma unroll
        for (int nt = 0; nt < 8; nt++) {
            s16x8 b = *(const s16x8*)&Wb[(((nt * 4 + kc) * 4 + q) * 16 + ml) * 8];
            acc[nt] = __builtin_amdgcn_mfma_f32_16x16x32_bf16(a, b, acc[nt], 0, 0, 0);
        }
    }
    __syncthreads();  // all W-frag reads done; reuse WC as C tile
    float* Cs = WC;   // [64][132]
#pragma unroll
    for (int nt = 0; nt < 8; nt++)
#pragma unroll
        for (int rr = 0; rr < 4; rr++)
            Cs[(wv * 16 + q * 4 + rr) * 132 + nt * 16 + ml] = acc[nt][rr];
    __syncthreads();

    float csum[4] = {0, 0, 0, 0}, csq[4] = {0, 0, 0, 0};
#pragma unroll
    for (int it = 0; it < 8; ++it) {
        int f = t * 4 + it * 1024;
        int r = f >> 7, c = f & 127;
        int row = row0 + r;
        if (row < n) {
            float4 v = *(float4*)&Cs[r * 132 + c];
            if (!AFFINE) {
                v.x += bias[c];
                v.y += bias[c + 1];
                v.z += bias[c + 2];
                v.w += bias[c + 3];
            }
            if (OUTBF16) {
                uint2 p;
                p.x = bf16pack(v.x, v.y);
                p.y = bf16pack(v.z, v.w);
                int qq = c >> 5;
                *(uint2*)&((unsigned*)outv)[(size_t)qq * N_NODES * 16 + (size_t)row * 16 +
                                            ((c & 31) >> 1)] = p;
            } else {
                *(float4*)&((float*)outv)[(size_t)row * 128 + c] = v;
            }
            if (STATS) {
                csum[0] += v.x; csq[0] += v.x * v.x;
                csum[1] += v.y; csq[1] += v.y * v.y;
                csum[2] += v.z; csq[2] += v.z * v.z;
                csum[3] += v.w; csq[3] += v.w * v.w;
            }
        }
    }
    if (STATS) {
        __syncthreads();
        if (t < 128) { affg[t] = 0.f; affb[t] = 0.f; }
        __syncthreads();
        int c = (t & 31) * 4;
#pragma unroll
        for (int j = 0; j < 4; j++) {
            atomicAdd(&affg[c + j], csum[j]);
            atomicAdd(&affb[c + j], csq[j]);
        }
        __syncthreads();
        if (t < 128) {
            atomicAdd(&stats_out[t], affg[t]);
            atomicAdd(&stats_out[128 + t], affb[t]);
        }
    }
}

// ---------------- fp32 GEMM (post FC only: 256 rows) ----------------
template <bool STATS, bool BIAS>
__global__ __launch_bounds__(256) void gemm128(const float* __restrict__ A, int n,
                                               const float* __restrict__ W,
                                               const float* __restrict__ bias,
                                               float* __restrict__ out,
                                               float* __restrict__ stats) {
    __shared__ float As[128][64];
    __shared__ float Ws[128][64];
    int tid = threadIdx.x;
    int row0 = blockIdx.y * 64;
    int col0 = blockIdx.x * 64;
    {
        int rsub = tid >> 5;
        int k4 = (tid & 31) * 4;
        for (int it = 0; it < 8; ++it) {
            int r = it * 8 + rsub;
            int row = row0 + r;
            float4 v = make_float4(0.f, 0.f, 0.f, 0.f);
            if (row < n) v = *(const float4*)&A[(size_t)row * 128 + k4];
            As[k4 + 0][r] = v.x;
            As[k4 + 1][r] = v.y;
            As[k4 + 2][r] = v.z;
            As[k4 + 3][r] = v.w;
        }
    }
    {
        int krow = tid >> 4;
        int c4 = (tid & 15) * 4;
        for (int it = 0; it < 8; ++it) {
            int k = it * 16 + krow;
            *(float4*)&Ws[k][c4] = *(const float4*)&W[k * 128 + col0 + c4];
        }
    }
    __syncthreads();
    int ty = tid >> 4, tx = tid & 15;
    float acc[4][4];
#pragma unroll
    for (int i = 0; i < 4; i++)
#pragma unroll
        for (int j = 0; j < 4; j++) acc[i][j] = 0.f;
#pragma unroll 4
    for (int k = 0; k < 128; k++) {
        float4 a = *(const float4*)&As[k][ty * 4];
        float4 b = *(const float4*)&Ws[k][tx * 4];
        float av[4] = {a.x, a.y, a.z, a.w};
        float bv[4] = {b.x, b.y, b.z, b.w};
#pragma unroll
        for (int i = 0; i < 4; i++)
#pragma unroll
            for (int j = 0; j < 4; j++) acc[i][j] += av[i] * bv[j];
    }
    float csum[4] = {0, 0, 0, 0}, csq[4] = {0, 0, 0, 0};
#pragma unroll
    for (int i = 0; i < 4; i++) {
        int row = row0 + ty * 4 + i;
        if (row < n) {
#pragma unroll
            for (int j = 0; j < 4; j++) {
                float v = acc[i][j];
                if (BIAS) v += bias[col0 + tx * 4 + j];
                out[(size_t)row * 128 + col0 + tx * 4 + j] = v;
                if (STATS) { csum[j] += v; csq[j] += v * v; }
            }
        }
    }
    if (STATS) {
        float* ps = &As[0][0];
        float* pq = &As[0][0] + 64;
        __syncthreads();
        if (tid < 64) { ps[tid] = 0.f; pq[tid] = 0.f; }
        __syncthreads();
#pragma unroll
        for (int j = 0; j < 4; j++) {
            atomicAdd(&ps[tx * 4 + j], csum[j]);
            atomicAdd(&pq[tx * 4 + j], csq[j]);
        }
        __syncthreads();
        if (tid < 64) {
            atomicAdd(&stats[col0 + tid], ps[tid]);
            atomicAdd(&stats[128 + col0 + tid], pq[tid]);
        }
    }
}

// ---------------- BN affine param kernel (post FC only) ----------------
__global__ void affine_kernel(const float* __restrict__ stats, const float* __restrict__ s,
                              const float* __restrict__ b, float* __restrict__ aff, float invN) {
    int i = threadIdx.x;  // 128
    float mean = stats[i] * invN;
    float var = fmaxf(stats[128 + i] * invN - mean * mean, 0.f);
    float g = s[i] * rsqrtf(var + EPSV);
    aff[i] = g;
    aff[128 + i] = b[i] - mean * g;
}

// ---------------- feature-quartered aggregation ----------------
// Quarter q table = 50K x 32feat bf16 = 3.2MB < 4MB per-XCD L2. Blocks pinned to an
// XCD pair via q=(blockIdx%8)>>1 (round-robin block->XCD heuristic). Lane layout:
// group g=lane>>4 handles edge eb+g (and eb+4+g), u=lane&15 handles feature-pair u.
__global__ __launch_bounds__(256) void aggq_kernel(const unsigned* __restrict__ hQ,
                                                   const int* __restrict__ rowptr,
                                                   const uint2* __restrict__ edat,
                                                   const float* __restrict__ dinv,
                                                   const float* __restrict__ convb,
                                                   float* __restrict__ out,
                                                   float* __restrict__ stats) {
    __shared__ float ps[4][64];
    int b = blockIdx.x;
    int w8 = b & 7;
    int q = w8 >> 1;
    int bq = ((b >> 3) << 1) | (w8 & 1);  // 0..511 within quarter
    int wave = threadIdx.x >> 6, lane = threadIdx.x & 63;
    int g = lane >> 4, u = lane & 15;
    const unsigned* hq = hQ + (size_t)q * N_NODES * 16;
    float2 bb = *(const float2*)&convb[q * 32 + (u << 1)];
    float sum0 = 0, sum1 = 0, sq0 = 0, sq1 = 0;
    for (int i = bq * 4 + wave; i < N_NODES; i += 2048) {
        float di = dinv[i];
        float sn = 2.0f * di * di;
        float2 hv = bf16unpack(hq[(size_t)i * 16 + u]);
        float ax = (g == 0) ? sn * hv.x : 0.f;
        float ay = (g == 0) ? sn * hv.y : 0.f;
        float ax2 = 0.f, ay2 = 0.f;
        int e = rowptr[i], end = rowptr[i + 1];
        for (int eb = e; eb < end; eb += 8) {
            int e1 = eb + g, e2 = eb + 4 + g;
            uint2 a1 = (e1 < end) ? edat[e1] : make_uint2(0u, 0u);
            uint2 a2 = (e2 < end) ? edat[e2] : make_uint2(0u, 0u);
            float2 h1 = bf16unpack(hq[(size_t)a1.x * 16 + u]);
            float2 h2 = bf16unpack(hq[(size_t)a2.x * 16 + u]);
            float n1 = __uint_as_float(a1.y), n2 = __uint_as_float(a2.y);
            ax += n1 * h1.x;
            ay += n1 * h1.y;
            ax2 += n2 * h2.x;
            ay2 += n2 * h2.y;
        }
        ax += ax2;
        ay += ay2;
        ax += __shfl_xor(ax, 16);
        ax += __shfl_xor(ax, 32);
        ay += __shfl_xor(ay, 16);
        ay += __shfl_xor(ay, 32);
        if (g == 0) {
            float ox = ax + bb.x, oy = ay + bb.y;
            *(float2*)&out[(size_t)i * 128 + q * 32 + (u << 1)] = make_float2(ox, oy);
            sum0 += ox;
            sum1 += oy;
            sq0 += ox * ox;
            sq1 += oy * oy;
        }
    }
    if (g == 0) {
        ps[wave][u * 4 + 0] = sum0;
        ps[wave][u * 4 + 1] = sum1;
        ps[wave][u * 4 + 2] = sq0;
        ps[wave][u * 4 + 3] = sq1;
    }
    __syncthreads();
    int t = threadIdx.x;
    if (t < 64) {
        float v = ps[0][t] + ps[1][t] + ps[2][t] + ps[3][t];
        int uu = t >> 2, k = t & 3;
        atomicAdd(&stats[(k >> 1) * 128 + q * 32 + (uu << 1) + (k & 1)], v);
    }
}

// ---------------- pooling: aff computed in-kernel from stats4 ----------------
__global__ __launch_bounds__(256) void pool_kernel(const float* __restrict__ h,
                                                   const float* __restrict__ stats_in,
                                                   const float* __restrict__ bn_sc,
                                                   const float* __restrict__ bn_bi,
                                                   const int* __restrict__ batch,
                                                   float* __restrict__ pooled,
                                                   float* __restrict__ cnt) {
    int base = blockIdx.x * 256;
    if (base >= N_NODES) return;
    __shared__ float affg[128], affb[128];
    if (threadIdx.x < 128) {
        int i = threadIdx.x;
        float mean = stats_in[i] * (1.0f / N_NODES);
        float var = fmaxf(stats_in[128 + i] * (1.0f / N_NODES) - mean * mean, 0.f);
        float g = bn_sc[i] * rsqrtf(var + EPSV);
        affg[i] = g;
        affb[i] = bn_bi[i] - mean * g;
    }
    __syncthreads();
    int last = min(base + 255, N_NODES - 1);
    int bmin = batch[base], bmax = batch[last];
    int wave = threadIdx.x >> 6, lane = threadIdx.x & 63;
    int d0 = lane * 2;
    __shared__ float acc[4][128];
    __shared__ int ccnt[4];
    float ga0 = affg[d0], ga1 = affg[d0 + 1];
    float gb0 = affb[d0], gb1 = affb[d0 + 1];
    for (int g = bmin; g <= bmax; ++g) {
        float ax = 0.f, ay = 0.f;
        int local = 0;
        for (int j = wave; j < 256; j += 4) {
            int i = base + j;
            if (i < N_NODES && batch[i] == g) {
                float2 hv = *(const float2*)&h[(size_t)i * 128 + d0];
                ax += fmaxf(hv.x * ga0 + gb0, 0.f);
                ay += fmaxf(hv.y * ga1 + gb1, 0.f);
                local++;
            }
        }
        acc[wave][d0] = ax;
        acc[wave][d0 + 1] = ay;
        if (lane == 0) ccnt[wave] = local;
        __syncthreads();
        if (threadIdx.x < 128) {
            float t = acc[0][threadIdx.x] + acc[1][threadIdx.x] + acc[2][threadIdx.x] +
                      acc[3][threadIdx.x];
            atomicAdd(&pooled[g * 128 + threadIdx.x], t);
        } else if (threadIdx.x == 128) {
            atomicAdd(&cnt[g], (float)(ccnt[0] + ccnt[1] + ccnt[2] + ccnt[3]));
        }
        __syncthreads();
    }
}

__global__ void pooldiv_kernel(float* __restrict__ pooled, const float* __restrict__ cnt) {
    int idx = blockIdx.x * 256 + threadIdx.x;
    if (idx < GG * 128) {
        int g = idx >> 7;
        pooled[idx] *= 1.0f / fmaxf(cnt[g], 1.0f);
    }
}

// ---------------- output head ----------------
__global__ void out_kernel(const float* __restrict__ Z, const float* __restrict__ aff,
                           const float* __restrict__ outW, const float* __restrict__ outb,
                           float* __restrict__ out) {
    int g = blockIdx.x;
    int lane = threadIdx.x;  // 64
    int d0 = lane * 2;
    float2 z = *(const float2*)&Z[(size_t)g * 128 + d0];
    float s = fmaxf(z.x * aff[d0] + aff[128 + d0], 0.f) * outW[d0] +
              fmaxf(z.y * aff[d0 + 1] + aff[128 + d0 + 1], 0.f) * outW[d0 + 1];
    for (int off = 32; off; off >>= 1) s += __shfl_down(s, off);
    if (lane == 0) out[g] = s + outb[0];
}

// ---------------- host ----------------
extern "C" void kernel_launch(void* const* d_in, const int* in_sizes, int n_in,
                              void* d_out, int out_size, void* d_ws, size_t ws_size,
                              hipStream_t stream) {
    const float* x         = (const float*)d_in[0];
    const int*   ei        = (const int*)d_in[1];
    const float* ew        = (const float*)d_in[2];
    const int*   batch     = (const int*)d_in[3];
    const float* pre_W     = (const float*)d_in[4];
    const float* pre_b     = (const float*)d_in[5];
    const float* pre_bn_s  = (const float*)d_in[6];
    const float* pre_bn_b  = (const float*)d_in[7];
    const float* convW     = (const float*)d_in[8];
    const float* convb     = (const float*)d_in[9];
    const float* bn_s      = (const float*)d_in[10];
    const float* bn_b      = (const float*)d_in[11];
    const float* post_W    = (const float*)d_in[12];
    const float* post_b    = (const float*)d_in[13];
    const float* post_bn_s = (const float*)d_in[14];
    const float* post_bn_b = (const float*)d_in[15];
    const float* out_W     = (const float*)d_in[16];
    const float* out_b     = (const float*)d_in[17];

    float* ws = (float*)d_ws;
    float* cd     = ws;                        // 2N (counts/deg interleaved, zeroed)
    float* stats  = ws + 2 * N_NODES;          // 6*256 (zeroed)
    float* pooled = stats + 6 * 256;           // 256*128 (zeroed)
    float* cnt    = pooled + GG * 128;         // 256 (zeroed)
    size_t zero_floats = 2 * N_NODES + 6 * 256 + GG * 128 + GG;
    float* Z      = cnt + GG;                  // 256*128
    float* aff    = Z + GG * 128;              // 256 (post only)
    int*   rowptr = (int*)(aff + 256);         // N+1
    int*   cursor = rowptr + N_NODES + 1;      // N
    int*   bsums  = cursor + N_NODES;          // NB
    int*   boffs  = bsums + NB;                // NB
    size_t woff = (size_t)((float*)(boffs + NB) - ws);
    woff = (woff + 3) & ~(size_t)3;            // 16B align for uint4
    unsigned short* Wf = (unsigned short*)(ws + woff);  // 5*16384 ushort
    size_t eoff = woff + 40960;
    eoff = (eoff + 1) & ~(size_t)1;            // 8B align
    uint2* edat   = (uint2*)(ws + eoff);       // E uint2
    float* dinv   = ws + eoff + 2 * (size_t)N_EDGES;  // N
    size_t off = eoff + 2 * (size_t)N_EDGES + N_NODES;
    off = (off + 3) & ~(size_t)3;
    float* hA = ws + off;                                    // N*128 fp32
    unsigned* hB = (unsigned*)(hA + (size_t)N_NODES * 128);  // 4 quarters x N x 16 uints

    hipMemsetAsync(d_ws, 0, zero_floats * sizeof(float), stream);
    wprep_kernel<<<320, 256, 0, stream>>>(pre_W, convW, Wf);
    count_deg_kernel<<<(N_EDGES + 255) / 256, 256, 0, stream>>>(ei, ew, cd);
    dinv_kernel<<<(N_NODES + 255) / 256, 256, 0, stream>>>(cd, dinv);
    blocksum_kernel<<<NB, 256, 0, stream>>>(cd, bsums);
    scan_bsums_kernel<<<1, 256, 0, stream>>>(bsums, boffs, rowptr);
    rowptr_kernel<<<NB, 256, 0, stream>>>(cd, boffs, rowptr, cursor);
    fill_kernel<<<(N_EDGES + 255) / 256, 256, 0, stream>>>(ei, ew, dinv, cursor, edat);

    // pre FC: hA = x @ pre_W + pre_b (MFMA bf16), stats0
    gemm_mfma<false, true, false><<<GEMM_BLOCKS, 256, 0, stream>>>(
        x, N_NODES, (const uint4*)Wf, nullptr, nullptr, nullptr, pre_b, hA, stats + 0);
    for (int l = 0; l < LL; l++) {
        const float* sc = (l == 0) ? pre_bn_s : bn_s + (l - 1) * 128;
        const float* bi = (l == 0) ? pre_bn_b : bn_b + (l - 1) * 128;
        // hB = bf16(relu(bn(hA)) @ convW[l]) in quarter-major layout
        gemm_mfma<true, false, true><<<GEMM_BLOCKS, 256, 0, stream>>>(
            hA, N_NODES, (const uint4*)(Wf + (size_t)(1 + l) * 16384), stats + l * 256, sc, bi,
            nullptr, hB, nullptr);
        // hA = scatter(hB) + convb[l], stats_{l+1} (feature-quartered, XCD-pinned)
        aggq_kernel<<<AGGQ_BLOCKS, 256, 0, stream>>>(hB, rowptr, edat, dinv, convb + l * 128, hA,
                                                     stats + (l + 1) * 256);
    }
    // mean pool of relu(bn(hA)) -- aff from stats4 in-kernel
    pool_kernel<<<(N_NODES + 255) / 256, 256, 0, stream>>>(hA, stats + 4 * 256, bn_s + 3 * 128,
                                                           bn_b + 3 * 128, batch, pooled, cnt);
    pooldiv_kernel<<<(GG * 128 + 255) / 256, 256, 0, stream>>>(pooled, cnt);
    // post FC (fp32, tiny)
    dim3 gP(2, 4);
    gemm128<true, true><<<gP, 256, 0, stream>>>(pooled, GG, post_W, post_b, Z, stats + 5 * 256);
    affine_kernel<<<1, 128, 0, stream>>>(stats + 5 * 256, post_bn_s, post_bn_b, aff,
                                         1.0f / GG);
    out_kernel<<<GG, 64, 0, stream>>>(Z, aff, out_W, out_b, (float*)d_out);
}

// Round 8
// 706.260 us; speedup vs baseline: 1.0062x; 1.0062x over previous
//
#include <hip/hip_runtime.h>

#define N_NODES 50000
#define N_EDGES 800000
#define DD 128
#define GG 256
#define LL 4
#define EPSV 1e-5f
#define NB 196  // ceil(N_NODES/256)
#define AGG_BLOCKS 1024   // 4096 waves x 13-node contiguous chunks
#define AGG_CHUNK 13      // 4096*13 = 53248 >= 50000
#define GEMM_BLOCKS 782   // ceil(N/64)

typedef __attribute__((ext_vector_type(8))) short s16x8;    // 8 bf16 (4 VGPRs)
typedef __attribute__((ext_vector_type(4))) float f32x4;    // 4 fp32 acc

// ---------------- bf16 helpers ----------------
static __device__ __forceinline__ unsigned bf16pack(float a, float b) {
    unsigned ua = __float_as_uint(a), ub = __float_as_uint(b);
    ua = (ua + 0x7FFFu + ((ua >> 16) & 1u)) >> 16;  // RNE
    ub = (ub + 0x7FFFu + ((ub >> 16) & 1u)) >> 16;
    return ua | (ub << 16);
}
static __device__ __forceinline__ unsigned short bf16r(float a) {
    unsigned u = __float_as_uint(a);
    u = (u + 0x7FFFu + ((u >> 16) & 1u)) >> 16;
    return (unsigned short)u;
}
static __device__ __forceinline__ float2 bf16unpack(unsigned u) {
    float2 r;
    r.x = __uint_as_float(u << 16);
    r.y = __uint_as_float(u & 0xFFFF0000u);
    return r;
}

// ---------------- setup kernels ----------------

__global__ void count_deg_kernel(const int* __restrict__ ei, const float* __restrict__ w,
                                 float* __restrict__ cd) {
    int e = blockIdx.x * 256 + threadIdx.x;
    if (e < N_EDGES) {
        int d = ei[N_EDGES + e];
        atomicAdd(&((int*)cd)[2 * d], 1);
        atomicAdd(&cd[2 * d + 1], w[e]);
    }
}

__global__ void dinv_kernel(const float* __restrict__ cd, float* __restrict__ dinv) {
    int i = blockIdx.x * 256 + threadIdx.x;
    if (i < N_NODES) {
        float d = cd[2 * i + 1] + 2.0f;  // self-loop weight 2.0
        dinv[i] = rsqrtf(fmaxf(d, EPSV));
    }
}

__global__ __launch_bounds__(256) void blocksum_kernel(const float* __restrict__ cd,
                                                       int* __restrict__ bsums) {
    int i = blockIdx.x * 256 + threadIdx.x;
    int v = (i < N_NODES) ? ((const int*)cd)[2 * i] : 0;
    for (int off = 32; off; off >>= 1) v += __shfl_down(v, off);
    __shared__ int s[4];
    if ((threadIdx.x & 63) == 0) s[threadIdx.x >> 6] = v;
    __syncthreads();
    if (threadIdx.x == 0) bsums[blockIdx.x] = s[0] + s[1] + s[2] + s[3];
}

__global__ __launch_bounds__(256) void scan_bsums_kernel(const int* __restrict__ bsums,
                                                         int* __restrict__ boffs,
                                                         int* __restrict__ rowptr) {
    __shared__ int s[256];
    int t = threadIdx.x;
    int v = (t < NB) ? bsums[t] : 0;
    s[t] = v;
    __syncthreads();
    for (int off = 1; off < 256; off <<= 1) {
        int u = (t >= off) ? s[t - off] : 0;
        __syncthreads();
        s[t] += u;
        __syncthreads();
    }
    if (t < NB) boffs[t] = s[t] - v;  // exclusive
    if (t == 0) rowptr[N_NODES] = N_EDGES;
}

__global__ __launch_bounds__(256) void rowptr_kernel(const float* __restrict__ cd,
                                                     const int* __restrict__ boffs,
                                                     int* __restrict__ rowptr,
                                                     int* __restrict__ cursor) {
    __shared__ int s[256];
    int i = blockIdx.x * 256 + threadIdx.x;
    int t = threadIdx.x;
    int c = (i < N_NODES) ? ((const int*)cd)[2 * i] : 0;
    s[t] = c;
    __syncthreads();
    for (int off = 1; off < 256; off <<= 1) {
        int u = (t >= off) ? s[t - off] : 0;
        __syncthreads();
        s[t] += u;
        __syncthreads();
    }
    if (i < N_NODES) {
        int r = boffs[blockIdx.x] + s[t] - c;
        rowptr[i] = r;
        cursor[i] = r;
    }
}

__global__ void fill_kernel(const int* __restrict__ ei, const float* __restrict__ w,
                            const float* __restrict__ dinv, int* __restrict__ cursor,
                            uint2* __restrict__ edat) {
    int e = blockIdx.x * 256 + threadIdx.x;
    if (e < N_EDGES) {
        int s_ = ei[e];
        int d = ei[N_EDGES + e];
        int pos = atomicAdd(&cursor[d], 1);
        edat[pos] = make_uint2((unsigned)s_, __float_as_uint(dinv[s_] * w[e] * dinv[d]));
    }
}

// ---------------- weight prep: fp32 W[k][n] -> fragment-ordered bf16 ----------------
__global__ void wprep_kernel(const float* __restrict__ preW, const float* __restrict__ convW,
                             unsigned short* __restrict__ Wf) {
    int idx = blockIdx.x * 256 + threadIdx.x;  // 5*16384
    if (idx >= 5 * 16384) return;
    int l = idx >> 14, kn = idx & 16383;
    int k = kn >> 7, nn = kn & 127;
    float v = (l == 0) ? preW[kn] : convW[(l - 1) * 16384 + kn];
    int nt = nn >> 4, nl = nn & 15, kc = k >> 5, q = (k >> 3) & 3, j = k & 7;
    Wf[(size_t)l * 16384 + ((((nt * 4 + kc) * 4 + q) * 16 + nl) * 8 + j)] = bf16r(v);
}

// ---------------- MFMA GEMM: out[n,128] = act(A)[n,128] @ W[128,128] ----------------
// OUTBF16 writes row-major packed bf16 pairs (64 uints/row).
template <bool AFFINE, bool STATS, bool OUTBF16>
__global__ __launch_bounds__(256) void gemm_mfma(const float* __restrict__ A, int n,
                                                 const uint4* __restrict__ Wf,
                                                 const float* __restrict__ stats_in,
                                                 const float* __restrict__ bn_sc,
                                                 const float* __restrict__ bn_bi,
                                                 const float* __restrict__ bias,
                                                 void* __restrict__ outv,
                                                 float* __restrict__ stats_out) {
    __shared__ unsigned short Af[8192];  // A frags
    __shared__ float WC[8448];           // W frags then C tile 64x132
    __shared__ float affg[128], affb[128];
    int t = threadIdx.x;
    int row0 = blockIdx.x * 64;

    if (AFFINE) {
        if (t < 128) {
            float mean = stats_in[t] * (1.0f / N_NODES);
            float var = fmaxf(stats_in[128 + t] * (1.0f / N_NODES) - mean * mean, 0.f);
            float g = bn_sc[t] * rsqrtf(var + EPSV);
            affg[t] = g;
            affb[t] = bn_bi[t] - mean * g;
        }
        __syncthreads();
    }
    {  // stage W fragments
        uint4* Wl = (uint4*)WC;
#pragma unroll
        for (int it = 0; it < 8; ++it) Wl[t + it * 256] = Wf[t + it * 256];
    }
    {  // stage A into fragment order (bf16), affine+relu fused
#pragma unroll
        for (int it = 0; it < 8; ++it) {
            int f = t * 4 + it * 1024;
            int r = f >> 7, c = f & 127;
            int row = row0 + r;
            float4 v = make_float4(0.f, 0.f, 0.f, 0.f);
            if (row < n) v = *(const float4*)&A[(size_t)row * 128 + c];
            if (AFFINE) {
                float4 g = *(float4*)&affg[c];
                float4 bb = *(float4*)&affb[c];
                v.x = fmaxf(v.x * g.x + bb.x, 0.f);
                v.y = fmaxf(v.y * g.y + bb.y, 0.f);
                v.z = fmaxf(v.z * g.z + bb.z, 0.f);
                v.w = fmaxf(v.w * g.w + bb.w, 0.f);
            }
            int w = r >> 4, mrow = r & 15, kc = c >> 5, q = (c >> 3) & 3, jo = c & 7;
            unsigned short* dst = &Af[(((w * 4 + kc) * 4 + q) * 16 + mrow) * 8 + jo];
            *(uint2*)dst = make_uint2(bf16pack(v.x, v.y), bf16pack(v.z, v.w));
        }
    }
    __syncthreads();

    int wv = t >> 6, lane = t & 63, q = lane >> 4, ml = lane & 15;
    f32x4 acc[8];
#pragma unroll
    for (int nt = 0; nt < 8; nt++) acc[nt] = (f32x4){0.f, 0.f, 0.f, 0.f};
    const unsigned short* Wb = (const unsigned short*)WC;
#pragma unroll
    for (int kc = 0; kc < 4; kc++) {
        s16x8 a = *(const s16x8*)&Af[(((wv * 4 + kc) * 4 + q) * 16 + ml) * 8];
#pragma unroll
        for (int nt = 0; nt < 8; nt++) {
            s16x8 b = *(const s16x8*)&Wb[(((nt * 4 + kc) * 4 + q) * 16 + ml) * 8];
            acc[nt] = __builtin_amdgcn_mfma_f32_16x16x32_bf16(a, b, acc[nt], 0, 0, 0);
        }
    }
    __syncthreads();  // all W-frag reads done; reuse WC as C tile
    float* Cs = WC;   // [64][132]
#pragma unroll
    for (int nt = 0; nt < 8; nt++)
#pragma unroll
        for (int rr = 0; rr < 4; rr++)
            Cs[(wv * 16 + q * 4 + rr) * 132 + nt * 16 + ml] = acc[nt][rr];
    __syncthreads();

    float csum[4] = {0, 0, 0, 0}, csq[4] = {0, 0, 0, 0};
#pragma unroll
    for (int it = 0; it < 8; ++it) {
        int f = t * 4 + it * 1024;
        int r = f >> 7, c = f & 127;
        int row = row0 + r;
        if (row < n) {
            float4 v = *(float4*)&Cs[r * 132 + c];
            if (!AFFINE) {
                v.x += bias[c];
                v.y += bias[c + 1];
                v.z += bias[c + 2];
                v.w += bias[c + 3];
            }
            if (OUTBF16) {
                uint2 p;
                p.x = bf16pack(v.x, v.y);
                p.y = bf16pack(v.z, v.w);
                *(uint2*)&((unsigned*)outv)[(size_t)row * 64 + (c >> 1)] = p;
            } else {
                *(float4*)&((float*)outv)[(size_t)row * 128 + c] = v;
            }
            if (STATS) {
                csum[0] += v.x; csq[0] += v.x * v.x;
                csum[1] += v.y; csq[1] += v.y * v.y;
                csum[2] += v.z; csq[2] += v.z * v.z;
                csum[3] += v.w; csq[3] += v.w * v.w;
            }
        }
    }
    if (STATS) {
        __syncthreads();
        if (t < 128) { affg[t] = 0.f; affb[t] = 0.f; }
        __syncthreads();
        int c = (t & 31) * 4;
#pragma unroll
        for (int j = 0; j < 4; j++) {
            atomicAdd(&affg[c + j], csum[j]);
            atomicAdd(&affb[c + j], csq[j]);
        }
        __syncthreads();
        if (t < 128) {
            atomicAdd(&stats_out[t], affg[t]);
            atomicAdd(&stats_out[128 + t], affb[t]);
        }
    }
}

// ---------------- fp32 GEMM (post FC only: 256 rows) ----------------
template <bool STATS, bool BIAS>
__global__ __launch_bounds__(256) void gemm128(const float* __restrict__ A, int n,
                                               const float* __restrict__ W,
                                               const float* __restrict__ bias,
                                               float* __restrict__ out,
                                               float* __restrict__ stats) {
    __shared__ float As[128][64];
    __shared__ float Ws[128][64];
    int tid = threadIdx.x;
    int row0 = blockIdx.y * 64;
    int col0 = blockIdx.x * 64;
    {
        int rsub = tid >> 5;
        int k4 = (tid & 31) * 4;
        for (int it = 0; it < 8; ++it) {
            int r = it * 8 + rsub;
            int row = row0 + r;
            float4 v = make_float4(0.f, 0.f, 0.f, 0.f);
            if (row < n) v = *(const float4*)&A[(size_t)row * 128 + k4];
            As[k4 + 0][r] = v.x;
            As[k4 + 1][r] = v.y;
            As[k4 + 2][r] = v.z;
            As[k4 + 3][r] = v.w;
        }
    }
    {
        int krow = tid >> 4;
        int c4 = (tid & 15) * 4;
        for (int it = 0; it < 8; ++it) {
            int k = it * 16 + krow;
            *(float4*)&Ws[k][c4] = *(const float4*)&W[k * 128 + col0 + c4];
        }
    }
    __syncthreads();
    int ty = tid >> 4, tx = tid & 15;
    float acc[4][4];
#pragma unroll
    for (int i = 0; i < 4; i++)
#pragma unroll
        for (int j = 0; j < 4; j++) acc[i][j] = 0.f;
#pragma unroll 4
    for (int k = 0; k < 128; k++) {
        float4 a = *(const float4*)&As[k][ty * 4];
        float4 b = *(const float4*)&Ws[k][tx * 4];
        float av[4] = {a.x, a.y, a.z, a.w};
        float bv[4] = {b.x, b.y, b.z, b.w};
#pragma unroll
        for (int i = 0; i < 4; i++)
#pragma unroll
            for (int j = 0; j < 4; j++) acc[i][j] += av[i] * bv[j];
    }
    float csum[4] = {0, 0, 0, 0}, csq[4] = {0, 0, 0, 0};
#pragma unroll
    for (int i = 0; i < 4; i++) {
        int row = row0 + ty * 4 + i;
        if (row < n) {
#pragma unroll
            for (int j = 0; j < 4; j++) {
                float v = acc[i][j];
                if (BIAS) v += bias[col0 + tx * 4 + j];
                out[(size_t)row * 128 + col0 + tx * 4 + j] = v;
                if (STATS) { csum[j] += v; csq[j] += v * v; }
            }
        }
    }
    if (STATS) {
        float* ps = &As[0][0];
        float* pq = &As[0][0] + 64;
        __syncthreads();
        if (tid < 64) { ps[tid] = 0.f; pq[tid] = 0.f; }
        __syncthreads();
#pragma unroll
        for (int j = 0; j < 4; j++) {
            atomicAdd(&ps[tx * 4 + j], csum[j]);
            atomicAdd(&pq[tx * 4 + j], csq[j]);
        }
        __syncthreads();
        if (tid < 64) {
            atomicAdd(&stats[col0 + tid], ps[tid]);
            atomicAdd(&stats[128 + col0 + tid], pq[tid]);
        }
    }
}

// ---------------- BN affine param kernel (post FC only) ----------------
__global__ void affine_kernel(const float* __restrict__ stats, const float* __restrict__ s,
                              const float* __restrict__ b, float* __restrict__ aff, float invN) {
    int i = threadIdx.x;  // 128
    float mean = stats[i] * invN;
    float var = fmaxf(stats[128 + i] * invN - mean * mean, 0.f);
    float g = s[i] * rsqrtf(var + EPSV);
    aff[i] = g;
    aff[128 + i] = b[i] - mean * g;
}

// ---------------- aggregation: wide-gather (16B/lane, 4 edges per VMEM instr) ----------
// Group g=lane>>4 owns edge eb+g; lane u=lane&15 covers features u*8..u*8+7 via one uint4
// (16 lanes x 16B = full 256B row). One gather instr serves 4 edges; one 8B broadcast
// load serves 4 edge records -> 0.5 VMEM instr/edge (R6/R7: ~2). Per-node shfl_xor reduce.
__global__ __launch_bounds__(256) void aggv_kernel(const unsigned* __restrict__ hT,
                                                   const int* __restrict__ rowptr,
                                                   const uint2* __restrict__ edat,
                                                   const float* __restrict__ dinv,
                                                   const float* __restrict__ convb,
                                                   float* __restrict__ out,
                                                   float* __restrict__ stats) {
    __shared__ float sbuf[256];
    int t = threadIdx.x;
    int wave = t >> 6, lane = t & 63;
    int g = lane >> 4, u = lane & 15;
    int wid = blockIdx.x * 4 + wave;
    int i0 = wid * AGG_CHUNK;
    int i1 = min(i0 + AGG_CHUNK, N_NODES);
    // per-lane bias for its 8 features (hoisted)
    float4 bb0 = *(const float4*)&convb[u * 8];
    float4 bb1 = *(const float4*)&convb[u * 8 + 4];
    float ssum[4] = {0, 0, 0, 0}, ssq[4] = {0, 0, 0, 0};  // stats for the 4 written feats (g<2)
    for (int i = i0; i < i1; ++i) {
        float acc[8];
#pragma unroll
        for (int k = 0; k < 8; k++) acc[k] = 0.f;
        int e = rowptr[i], end = rowptr[i + 1];
        for (int eb = e; eb < end; eb += 4) {
            int ee = eb + g;
            uint2 ed = (ee < end) ? edat[ee] : make_uint2(0u, 0u);
            float nrm = __uint_as_float(ed.y);
            uint4 hv = *(const uint4*)&hT[(size_t)ed.x * 64 + u * 4];
            float2 p0 = bf16unpack(hv.x), p1 = bf16unpack(hv.y);
            float2 p2 = bf16unpack(hv.z), p3 = bf16unpack(hv.w);
            acc[0] += nrm * p0.x; acc[1] += nrm * p0.y;
            acc[2] += nrm * p1.x; acc[3] += nrm * p1.y;
            acc[4] += nrm * p2.x; acc[5] += nrm * p2.y;
            acc[6] += nrm * p3.x; acc[7] += nrm * p3.y;
        }
#pragma unroll
        for (int k = 0; k < 8; k++) {
            acc[k] += __shfl_xor(acc[k], 16);
            acc[k] += __shfl_xor(acc[k], 32);
        }
        // self loop (added once, after reduce - all groups hold identical sums)
        float di = dinv[i];
        float sn = 2.0f * di * di;
        {
            uint4 hs = *(const uint4*)&hT[(size_t)i * 64 + u * 4];
            float2 p0 = bf16unpack(hs.x), p1 = bf16unpack(hs.y);
            float2 p2 = bf16unpack(hs.z), p3 = bf16unpack(hs.w);
            acc[0] += sn * p0.x; acc[1] += sn * p0.y;
            acc[2] += sn * p1.x; acc[3] += sn * p1.y;
            acc[4] += sn * p2.x; acc[5] += sn * p2.y;
            acc[6] += sn * p3.x; acc[7] += sn * p3.y;
        }
        acc[0] += bb0.x; acc[1] += bb0.y; acc[2] += bb0.z; acc[3] += bb0.w;
        acc[4] += bb1.x; acc[5] += bb1.y; acc[6] += bb1.z; acc[7] += bb1.w;
        if (g < 2) {  // groups 0/1 co-write the 512B row in one dwordx4 instr
            float4 wv = (g == 0) ? make_float4(acc[0], acc[1], acc[2], acc[3])
                                 : make_float4(acc[4], acc[5], acc[6], acc[7]);
            *(float4*)&out[(size_t)i * 128 + u * 8 + g * 4] = wv;
            ssum[0] += wv.x; ssq[0] += wv.x * wv.x;
            ssum[1] += wv.y; ssq[1] += wv.y * wv.y;
            ssum[2] += wv.z; ssq[2] += wv.z * wv.z;
            ssum[3] += wv.w; ssq[3] += wv.w * wv.w;
        }
    }
    // stats flush
    sbuf[t] = 0.f;
    __syncthreads();
    if (g < 2) {
        int f = u * 8 + g * 4;
#pragma unroll
        for (int j = 0; j < 4; j++) {
            atomicAdd(&sbuf[f + j], ssum[j]);
            atomicAdd(&sbuf[128 + f + j], ssq[j]);
        }
    }
    __syncthreads();
    atomicAdd(&stats[t], sbuf[t]);
}

// ---------------- pooling: aff computed in-kernel from stats4 ----------------
__global__ __launch_bounds__(256) void pool_kernel(const float* __restrict__ h,
                                                   const float* __restrict__ stats_in,
                                                   const float* __restrict__ bn_sc,
                                                   const float* __restrict__ bn_bi,
                                                   const int* __restrict__ batch,
                                                   float* __restrict__ pooled,
                                                   float* __restrict__ cnt) {
    int base = blockIdx.x * 256;
    if (base >= N_NODES) return;
    __shared__ float affg[128], affb[128];
    if (threadIdx.x < 128) {
        int i = threadIdx.x;
        float mean = stats_in[i] * (1.0f / N_NODES);
        float var = fmaxf(stats_in[128 + i] * (1.0f / N_NODES) - mean * mean, 0.f);
        float g = bn_sc[i] * rsqrtf(var + EPSV);
        affg[i] = g;
        affb[i] = bn_bi[i] - mean * g;
    }
    __syncthreads();
    int last = min(base + 255, N_NODES - 1);
    int bmin = batch[base], bmax = batch[last];
    int wave = threadIdx.x >> 6, lane = threadIdx.x & 63;
    int d0 = lane * 2;
    __shared__ float acc[4][128];
    __shared__ int ccnt[4];
    float ga0 = affg[d0], ga1 = affg[d0 + 1];
    float gb0 = affb[d0], gb1 = affb[d0 + 1];
    for (int g = bmin; g <= bmax; ++g) {
        float ax = 0.f, ay = 0.f;
        int local = 0;
        for (int j = wave; j < 256; j += 4) {
            int i = base + j;
            if (i < N_NODES && batch[i] == g) {
                float2 hv = *(const float2*)&h[(size_t)i * 128 + d0];
                ax += fmaxf(hv.x * ga0 + gb0, 0.f);
                ay += fmaxf(hv.y * ga1 + gb1, 0.f);
                local++;
            }
        }
        acc[wave][d0] = ax;
        acc[wave][d0 + 1] = ay;
        if (lane == 0) ccnt[wave] = local;
        __syncthreads();
        if (threadIdx.x < 128) {
            float t = acc[0][threadIdx.x] + acc[1][threadIdx.x] + acc[2][threadIdx.x] +
                      acc[3][threadIdx.x];
            atomicAdd(&pooled[g * 128 + threadIdx.x], t);
        } else if (threadIdx.x == 128) {
            atomicAdd(&cnt[g], (float)(ccnt[0] + ccnt[1] + ccnt[2] + ccnt[3]));
        }
        __syncthreads();
    }
}

__global__ void pooldiv_kernel(float* __restrict__ pooled, const float* __restrict__ cnt) {
    int idx = blockIdx.x * 256 + threadIdx.x;
    if (idx < GG * 128) {
        int g = idx >> 7;
        pooled[idx] *= 1.0f / fmaxf(cnt[g], 1.0f);
    }
}

// ---------------- output head ----------------
__global__ void out_kernel(const float* __restrict__ Z, const float* __restrict__ aff,
                           const float* __restrict__ outW, const float* __restrict__ outb,
                           float* __restrict__ out) {
    int g = blockIdx.x;
    int lane = threadIdx.x;  // 64
    int d0 = lane * 2;
    float2 z = *(const float2*)&Z[(size_t)g * 128 + d0];
    float s = fmaxf(z.x * aff[d0] + aff[128 + d0], 0.f) * outW[d0] +
              fmaxf(z.y * aff[d0 + 1] + aff[128 + d0 + 1], 0.f) * outW[d0 + 1];
    for (int off = 32; off; off >>= 1) s += __shfl_down(s, off);
    if (lane == 0) out[g] = s + outb[0];
}

// ---------------- host ----------------
extern "C" void kernel_launch(void* const* d_in, const int* in_sizes, int n_in,
                              void* d_out, int out_size, void* d_ws, size_t ws_size,
                              hipStream_t stream) {
    const float* x         = (const float*)d_in[0];
    const int*   ei        = (const int*)d_in[1];
    const float* ew        = (const float*)d_in[2];
    const int*   batch     = (const int*)d_in[3];
    const float* pre_W     = (const float*)d_in[4];
    const float* pre_b     = (const float*)d_in[5];
    const float* pre_bn_s  = (const float*)d_in[6];
    const float* pre_bn_b  = (const float*)d_in[7];
    const float* convW     = (const float*)d_in[8];
    const float* convb     = (const float*)d_in[9];
    const float* bn_s      = (const float*)d_in[10];
    const float* bn_b      = (const float*)d_in[11];
    const float* post_W    = (const float*)d_in[12];
    const float* post_b    = (const float*)d_in[13];
    const float* post_bn_s = (const float*)d_in[14];
    const float* post_bn_b = (const float*)d_in[15];
    const float* out_W     = (const float*)d_in[16];
    const float* out_b     = (const float*)d_in[17];

    float* ws = (float*)d_ws;
    float* cd     = ws;                        // 2N (counts/deg interleaved, zeroed)
    float* stats  = ws + 2 * N_NODES;          // 6*256 (zeroed)
    float* pooled = stats + 6 * 256;           // 256*128 (zeroed)
    float* cnt    = pooled + GG * 128;         // 256 (zeroed)
    size_t zero_floats = 2 * N_NODES + 6 * 256 + GG * 128 + GG;
    float* Z      = cnt + GG;                  // 256*128
    float* aff    = Z + GG * 128;              // 256 (post only)
    int*   rowptr = (int*)(aff + 256);         // N+1
    int*   cursor = rowptr + N_NODES + 1;      // N
    int*   bsums  = cursor + N_NODES;          // NB
    int*   boffs  = bsums + NB;                // NB
    size_t woff = (size_t)((float*)(boffs + NB) - ws);
    woff = (woff + 3) & ~(size_t)3;            // 16B align for uint4
    unsigned short* Wf = (unsigned short*)(ws + woff);  // 5*16384 ushort
    size_t eoff = woff + 40960;
    eoff = (eoff + 1) & ~(size_t)1;            // 8B align
    uint2* edat   = (uint2*)(ws + eoff);       // E uint2
    float* dinv   = ws + eoff + 2 * (size_t)N_EDGES;  // N
    size_t off = eoff + 2 * (size_t)N_EDGES + N_NODES;
    off = (off + 3) & ~(size_t)3;
    float* hA = ws + off;                                    // N*128 fp32
    unsigned* hB = (unsigned*)(hA + (size_t)N_NODES * 128);  // N*64 packed bf16 (16B-aligned)

    hipMemsetAsync(d_ws, 0, zero_floats * sizeof(float), stream);
    wprep_kernel<<<320, 256, 0, stream>>>(pre_W, convW, Wf);
    count_deg_kernel<<<(N_EDGES + 255) / 256, 256, 0, stream>>>(ei, ew, cd);
    dinv_kernel<<<(N_NODES + 255) / 256, 256, 0, stream>>>(cd, dinv);
    blocksum_kernel<<<NB, 256, 0, stream>>>(cd, bsums);
    scan_bsums_kernel<<<1, 256, 0, stream>>>(bsums, boffs, rowptr);
    rowptr_kernel<<<NB, 256, 0, stream>>>(cd, boffs, rowptr, cursor);
    fill_kernel<<<(N_EDGES + 255) / 256, 256, 0, stream>>>(ei, ew, dinv, cursor, edat);

    // pre FC: hA = x @ pre_W + pre_b (MFMA bf16), stats0
    gemm_mfma<false, true, false><<<GEMM_BLOCKS, 256, 0, stream>>>(
        x, N_NODES, (const uint4*)Wf, nullptr, nullptr, nullptr, pre_b, hA, stats + 0);
    for (int l = 0; l < LL; l++) {
        const float* sc = (l == 0) ? pre_bn_s : bn_s + (l - 1) * 128;
        const float* bi = (l == 0) ? pre_bn_b : bn_b + (l - 1) * 128;
        // hB = bf16(relu(bn(hA)) @ convW[l]) row-major
        gemm_mfma<true, false, true><<<GEMM_BLOCKS, 256, 0, stream>>>(
            hA, N_NODES, (const uint4*)(Wf + (size_t)(1 + l) * 16384), stats + l * 256, sc, bi,
            nullptr, hB, nullptr);
        // hA = scatter(hB) + convb[l], stats_{l+1} (wide-gather)
        aggv_kernel<<<AGG_BLOCKS, 256, 0, stream>>>(hB, rowptr, edat, dinv, convb + l * 128, hA,
                                                    stats + (l + 1) * 256);
    }
    // mean pool of relu(bn(hA)) -- aff from stats4 in-kernel
    pool_kernel<<<(N_NODES + 255) / 256, 256, 0, stream>>>(hA, stats + 4 * 256, bn_s + 3 * 128,
                                                           bn_b + 3 * 128, batch, pooled, cnt);
    pooldiv_kernel<<<(GG * 128 + 255) / 256, 256, 0, stream>>>(pooled, cnt);
    // post FC (fp32, tiny)
    dim3 gP(2, 4);
    gemm128<true, true><<<gP, 256, 0, stream>>>(pooled, GG, post_W, post_b, Z, stats + 5 * 256);
    affine_kernel<<<1, 128, 0, stream>>>(stats + 5 * 256, post_bn_s, post_bn_b, aff,
                                         1.0f / GG);
    out_kernel<<<GG, 64, 0, stream>>>(Z, aff, out_W, out_b, (float*)d_out);
}

// Round 9
// 690.083 us; speedup vs baseline: 1.0298x; 1.0234x over previous
//
#include <hip/hip_runtime.h>

#define N_NODES 50000
#define N_EDGES 800000
#define DD 128
#define GG 256
#define LL 4
#define EPSV 1e-5f
#define NB 196  // ceil(N_NODES/256)
#define AGG_BLOCKS 1024   // 4096 waves x 13-node contiguous chunks
#define AGG_CHUNK 13      // 4096*13 = 53248 >= 50000
#define GEMM_BLOCKS 782   // ceil(N/64)

typedef __attribute__((ext_vector_type(8))) short s16x8;    // 8 bf16 (4 VGPRs)
typedef __attribute__((ext_vector_type(4))) float f32x4;    // 4 fp32 acc

// ---------------- bf16 helpers ----------------
static __device__ __forceinline__ unsigned bf16pack(float a, float b) {
    unsigned ua = __float_as_uint(a), ub = __float_as_uint(b);
    ua = (ua + 0x7FFFu + ((ua >> 16) & 1u)) >> 16;  // RNE
    ub = (ub + 0x7FFFu + ((ub >> 16) & 1u)) >> 16;
    return ua | (ub << 16);
}
static __device__ __forceinline__ unsigned short bf16r(float a) {
    unsigned u = __float_as_uint(a);
    u = (u + 0x7FFFu + ((u >> 16) & 1u)) >> 16;
    return (unsigned short)u;
}
static __device__ __forceinline__ float2 bf16unpack(unsigned u) {
    float2 r;
    r.x = __uint_as_float(u << 16);
    r.y = __uint_as_float(u & 0xFFFF0000u);
    return r;
}

// ---------------- setup kernels ----------------

__global__ void count_deg_kernel(const int* __restrict__ ei, const float* __restrict__ w,
                                 float* __restrict__ cd) {
    int e = blockIdx.x * 256 + threadIdx.x;
    if (e < N_EDGES) {
        int d = ei[N_EDGES + e];
        atomicAdd(&((int*)cd)[2 * d], 1);
        atomicAdd(&cd[2 * d + 1], w[e]);
    }
}

__global__ __launch_bounds__(256) void blocksum_kernel(const float* __restrict__ cd,
                                                       int* __restrict__ bsums) {
    int i = blockIdx.x * 256 + threadIdx.x;
    int v = (i < N_NODES) ? ((const int*)cd)[2 * i] : 0;
    for (int off = 32; off; off >>= 1) v += __shfl_down(v, off);
    __shared__ int s[4];
    if ((threadIdx.x & 63) == 0) s[threadIdx.x >> 6] = v;
    __syncthreads();
    if (threadIdx.x == 0) bsums[blockIdx.x] = s[0] + s[1] + s[2] + s[3];
}

__global__ __launch_bounds__(256) void scan_bsums_kernel(const int* __restrict__ bsums,
                                                         int* __restrict__ boffs,
                                                         int* __restrict__ rowptr) {
    __shared__ int s[256];
    int t = threadIdx.x;
    int v = (t < NB) ? bsums[t] : 0;
    s[t] = v;
    __syncthreads();
    for (int off = 1; off < 256; off <<= 1) {
        int u = (t >= off) ? s[t - off] : 0;
        __syncthreads();
        s[t] += u;
        __syncthreads();
    }
    if (t < NB) boffs[t] = s[t] - v;  // exclusive
    if (t == 0) rowptr[N_NODES] = N_EDGES;
}

// per-block scan + block offset -> rowptr/cursor; dinv fused (per-node, deg final here)
__global__ __launch_bounds__(256) void rowptr_kernel(const float* __restrict__ cd,
                                                     const int* __restrict__ boffs,
                                                     int* __restrict__ rowptr,
                                                     int* __restrict__ cursor,
                                                     float* __restrict__ dinv) {
    __shared__ int s[256];
    int i = blockIdx.x * 256 + threadIdx.x;
    int t = threadIdx.x;
    int c = (i < N_NODES) ? ((const int*)cd)[2 * i] : 0;
    s[t] = c;
    __syncthreads();
    for (int off = 1; off < 256; off <<= 1) {
        int u = (t >= off) ? s[t - off] : 0;
        __syncthreads();
        s[t] += u;
        __syncthreads();
    }
    if (i < N_NODES) {
        int r = boffs[blockIdx.x] + s[t] - c;
        rowptr[i] = r;
        cursor[i] = r;
        float d = cd[2 * i + 1] + 2.0f;  // self-loop weight 2.0
        dinv[i] = rsqrtf(fmaxf(d, EPSV));
    }
}

__global__ void fill_kernel(const int* __restrict__ ei, const float* __restrict__ w,
                            const float* __restrict__ dinv, int* __restrict__ cursor,
                            uint2* __restrict__ edat) {
    int e = blockIdx.x * 256 + threadIdx.x;
    if (e < N_EDGES) {
        int s_ = ei[e];
        int d = ei[N_EDGES + e];
        int pos = atomicAdd(&cursor[d], 1);
        edat[pos] = make_uint2((unsigned)s_, __float_as_uint(dinv[s_] * w[e] * dinv[d]));
    }
}

// ---------------- weight prep: fp32 W[k][n] -> fragment-ordered bf16 ----------------
__global__ void wprep_kernel(const float* __restrict__ preW, const float* __restrict__ convW,
                             unsigned short* __restrict__ Wf) {
    int idx = blockIdx.x * 256 + threadIdx.x;  // 5*16384
    if (idx >= 5 * 16384) return;
    int l = idx >> 14, kn = idx & 16383;
    int k = kn >> 7, nn = kn & 127;
    float v = (l == 0) ? preW[kn] : convW[(l - 1) * 16384 + kn];
    int nt = nn >> 4, nl = nn & 15, kc = k >> 5, q = (k >> 3) & 3, j = k & 7;
    Wf[(size_t)l * 16384 + ((((nt * 4 + kc) * 4 + q) * 16 + nl) * 8 + j)] = bf16r(v);
}

// ---------------- MFMA GEMM: out[n,128] = act(A)[n,128] @ W[128,128] ----------------
template <bool AFFINE, bool STATS, bool OUTBF16>
__global__ __launch_bounds__(256) void gemm_mfma(const float* __restrict__ A, int n,
                                                 const uint4* __restrict__ Wf,
                                                 const float* __restrict__ stats_in,
                                                 const float* __restrict__ bn_sc,
                                                 const float* __restrict__ bn_bi,
                                                 const float* __restrict__ bias,
                                                 void* __restrict__ outv,
                                                 float* __restrict__ stats_out) {
    __shared__ unsigned short Af[8192];  // A frags
    __shared__ float WC[8448];           // W frags then C tile 64x132
    __shared__ float affg[128], affb[128];
    int t = threadIdx.x;
    int row0 = blockIdx.x * 64;

    if (AFFINE) {
        if (t < 128) {
            float mean = stats_in[t] * (1.0f / N_NODES);
            float var = fmaxf(stats_in[128 + t] * (1.0f / N_NODES) - mean * mean, 0.f);
            float g = bn_sc[t] * rsqrtf(var + EPSV);
            affg[t] = g;
            affb[t] = bn_bi[t] - mean * g;
        }
        __syncthreads();
    }
    {  // stage W fragments
        uint4* Wl = (uint4*)WC;
#pragma unroll
        for (int it = 0; it < 8; ++it) Wl[t + it * 256] = Wf[t + it * 256];
    }
    {  // stage A into fragment order (bf16), affine+relu fused
#pragma unroll
        for (int it = 0; it < 8; ++it) {
            int f = t * 4 + it * 1024;
            int r = f >> 7, c = f & 127;
            int row = row0 + r;
            float4 v = make_float4(0.f, 0.f, 0.f, 0.f);
            if (row < n) v = *(const float4*)&A[(size_t)row * 128 + c];
            if (AFFINE) {
                float4 g = *(float4*)&affg[c];
                float4 bb = *(float4*)&affb[c];
                v.x = fmaxf(v.x * g.x + bb.x, 0.f);
                v.y = fmaxf(v.y * g.y + bb.y, 0.f);
                v.z = fmaxf(v.z * g.z + bb.z, 0.f);
                v.w = fmaxf(v.w * g.w + bb.w, 0.f);
            }
            int w = r >> 4, mrow = r & 15, kc = c >> 5, q = (c >> 3) & 3, jo = c & 7;
            unsigned short* dst = &Af[(((w * 4 + kc) * 4 + q) * 16 + mrow) * 8 + jo];
            *(uint2*)dst = make_uint2(bf16pack(v.x, v.y), bf16pack(v.z, v.w));
        }
    }
    __syncthreads();

    int wv = t >> 6, lane = t & 63, q = lane >> 4, ml = lane & 15;
    f32x4 acc[8];
#pragma unroll
    for (int nt = 0; nt < 8; nt++) acc[nt] = (f32x4){0.f, 0.f, 0.f, 0.f};
    const unsigned short* Wb = (const unsigned short*)WC;
#pragma unroll
    for (int kc = 0; kc < 4; kc++) {
        s16x8 a = *(const s16x8*)&Af[(((wv * 4 + kc) * 4 + q) * 16 + ml) * 8];
#pragma unroll
        for (int nt = 0; nt < 8; nt++) {
            s16x8 b = *(const s16x8*)&Wb[(((nt * 4 + kc) * 4 + q) * 16 + ml) * 8];
            acc[nt] = __builtin_amdgcn_mfma_f32_16x16x32_bf16(a, b, acc[nt], 0, 0, 0);
        }
    }
    __syncthreads();  // all W-frag reads done; reuse WC as C tile
    float* Cs = WC;   // [64][132]
#pragma unroll
    for (int nt = 0; nt < 8; nt++)
#pragma unroll
        for (int rr = 0; rr < 4; rr++)
            Cs[(wv * 16 + q * 4 + rr) * 132 + nt * 16 + ml] = acc[nt][rr];
    __syncthreads();

    float csum[4] = {0, 0, 0, 0}, csq[4] = {0, 0, 0, 0};
#pragma unroll
    for (int it = 0; it < 8; ++it) {
        int f = t * 4 + it * 1024;
        int r = f >> 7, c = f & 127;
        int row = row0 + r;
        if (row < n) {
            float4 v = *(float4*)&Cs[r * 132 + c];
            if (!AFFINE) {
                v.x += bias[c];
                v.y += bias[c + 1];
                v.z += bias[c + 2];
                v.w += bias[c + 3];
            }
            if (OUTBF16) {
                uint2 p;
                p.x = bf16pack(v.x, v.y);
                p.y = bf16pack(v.z, v.w);
                *(uint2*)&((unsigned*)outv)[(size_t)row * 64 + (c >> 1)] = p;
            } else {
                *(float4*)&((float*)outv)[(size_t)row * 128 + c] = v;
            }
            if (STATS) {
                csum[0] += v.x; csq[0] += v.x * v.x;
                csum[1] += v.y; csq[1] += v.y * v.y;
                csum[2] += v.z; csq[2] += v.z * v.z;
                csum[3] += v.w; csq[3] += v.w * v.w;
            }
        }
    }
    if (STATS) {
        __syncthreads();
        if (t < 128) { affg[t] = 0.f; affb[t] = 0.f; }
        __syncthreads();
        int c = (t & 31) * 4;
#pragma unroll
        for (int j = 0; j < 4; j++) {
            atomicAdd(&affg[c + j], csum[j]);
            atomicAdd(&affb[c + j], csq[j]);
        }
        __syncthreads();
        if (t < 128) {
            atomicAdd(&stats_out[t], affg[t]);
            atomicAdd(&stats_out[128 + t], affb[t]);
        }
    }
}

// ---------------- fp32 GEMM (post FC only: 256 rows) ----------------
template <bool STATS, bool BIAS>
__global__ __launch_bounds__(256) void gemm128(const float* __restrict__ A, int n,
                                               const float* __restrict__ W,
                                               const float* __restrict__ bias,
                                               float* __restrict__ out,
                                               float* __restrict__ stats) {
    __shared__ float As[128][64];
    __shared__ float Ws[128][64];
    int tid = threadIdx.x;
    int row0 = blockIdx.y * 64;
    int col0 = blockIdx.x * 64;
    {
        int rsub = tid >> 5;
        int k4 = (tid & 31) * 4;
        for (int it = 0; it < 8; ++it) {
            int r = it * 8 + rsub;
            int row = row0 + r;
            float4 v = make_float4(0.f, 0.f, 0.f, 0.f);
            if (row < n) v = *(const float4*)&A[(size_t)row * 128 + k4];
            As[k4 + 0][r] = v.x;
            As[k4 + 1][r] = v.y;
            As[k4 + 2][r] = v.z;
            As[k4 + 3][r] = v.w;
        }
    }
    {
        int krow = tid >> 4;
        int c4 = (tid & 15) * 4;
        for (int it = 0; it < 8; ++it) {
            int k = it * 16 + krow;
            *(float4*)&Ws[k][c4] = *(const float4*)&W[k * 128 + col0 + c4];
        }
    }
    __syncthreads();
    int ty = tid >> 4, tx = tid & 15;
    float acc[4][4];
#pragma unroll
    for (int i = 0; i < 4; i++)
#pragma unroll
        for (int j = 0; j < 4; j++) acc[i][j] = 0.f;
#pragma unroll 4
    for (int k = 0; k < 128; k++) {
        float4 a = *(const float4*)&As[k][ty * 4];
        float4 b = *(const float4*)&Ws[k][tx * 4];
        float av[4] = {a.x, a.y, a.z, a.w};
        float bv[4] = {b.x, b.y, b.z, b.w};
#pragma unroll
        for (int i = 0; i < 4; i++)
#pragma unroll
            for (int j = 0; j < 4; j++) acc[i][j] += av[i] * bv[j];
    }
    float csum[4] = {0, 0, 0, 0}, csq[4] = {0, 0, 0, 0};
#pragma unroll
    for (int i = 0; i < 4; i++) {
        int row = row0 + ty * 4 + i;
        if (row < n) {
#pragma unroll
            for (int j = 0; j < 4; j++) {
                float v = acc[i][j];
                if (BIAS) v += bias[col0 + tx * 4 + j];
                out[(size_t)row * 128 + col0 + tx * 4 + j] = v;
                if (STATS) { csum[j] += v; csq[j] += v * v; }
            }
        }
    }
    if (STATS) {
        float* ps = &As[0][0];
        float* pq = &As[0][0] + 64;
        __syncthreads();
        if (tid < 64) { ps[tid] = 0.f; pq[tid] = 0.f; }
        __syncthreads();
#pragma unroll
        for (int j = 0; j < 4; j++) {
            atomicAdd(&ps[tx * 4 + j], csum[j]);
            atomicAdd(&pq[tx * 4 + j], csq[j]);
        }
        __syncthreads();
        if (tid < 64) {
            atomicAdd(&stats[col0 + tid], ps[tid]);
            atomicAdd(&stats[128 + col0 + tid], pq[tid]);
        }
    }
}

// ---------------- aggregation: wide-gather (R8; at the scattered-access floor) ----------
__global__ __launch_bounds__(256) void aggv_kernel(const unsigned* __restrict__ hT,
                                                   const int* __restrict__ rowptr,
                                                   const uint2* __restrict__ edat,
                                                   const float* __restrict__ dinv,
                                                   const float* __restrict__ convb,
                                                   float* __restrict__ out,
                                                   float* __restrict__ stats) {
    __shared__ float sbuf[256];
    int t = threadIdx.x;
    int wave = t >> 6, lane = t & 63;
    int g = lane >> 4, u = lane & 15;
    int wid = blockIdx.x * 4 + wave;
    int i0 = wid * AGG_CHUNK;
    int i1 = min(i0 + AGG_CHUNK, N_NODES);
    float4 bb0 = *(const float4*)&convb[u * 8];
    float4 bb1 = *(const float4*)&convb[u * 8 + 4];
    float ssum[4] = {0, 0, 0, 0}, ssq[4] = {0, 0, 0, 0};
    for (int i = i0; i < i1; ++i) {
        float acc[8];
#pragma unroll
        for (int k = 0; k < 8; k++) acc[k] = 0.f;
        int e = rowptr[i], end = rowptr[i + 1];
        for (int eb = e; eb < end; eb += 4) {
            int ee = eb + g;
            uint2 ed = (ee < end) ? edat[ee] : make_uint2(0u, 0u);
            float nrm = __uint_as_float(ed.y);
            uint4 hv = *(const uint4*)&hT[(size_t)ed.x * 64 + u * 4];
            float2 p0 = bf16unpack(hv.x), p1 = bf16unpack(hv.y);
            float2 p2 = bf16unpack(hv.z), p3 = bf16unpack(hv.w);
            acc[0] += nrm * p0.x; acc[1] += nrm * p0.y;
            acc[2] += nrm * p1.x; acc[3] += nrm * p1.y;
            acc[4] += nrm * p2.x; acc[5] += nrm * p2.y;
            acc[6] += nrm * p3.x; acc[7] += nrm * p3.y;
        }
#pragma unroll
        for (int k = 0; k < 8; k++) {
            acc[k] += __shfl_xor(acc[k], 16);
            acc[k] += __shfl_xor(acc[k], 32);
        }
        float di = dinv[i];
        float sn = 2.0f * di * di;
        {
            uint4 hs = *(const uint4*)&hT[(size_t)i * 64 + u * 4];
            float2 p0 = bf16unpack(hs.x), p1 = bf16unpack(hs.y);
            float2 p2 = bf16unpack(hs.z), p3 = bf16unpack(hs.w);
            acc[0] += sn * p0.x; acc[1] += sn * p0.y;
            acc[2] += sn * p1.x; acc[3] += sn * p1.y;
            acc[4] += sn * p2.x; acc[5] += sn * p2.y;
            acc[6] += sn * p3.x; acc[7] += sn * p3.y;
        }
        acc[0] += bb0.x; acc[1] += bb0.y; acc[2] += bb0.z; acc[3] += bb0.w;
        acc[4] += bb1.x; acc[5] += bb1.y; acc[6] += bb1.z; acc[7] += bb1.w;
        if (g < 2) {
            float4 wv = (g == 0) ? make_float4(acc[0], acc[1], acc[2], acc[3])
                                 : make_float4(acc[4], acc[5], acc[6], acc[7]);
            *(float4*)&out[(size_t)i * 128 + u * 8 + g * 4] = wv;
            ssum[0] += wv.x; ssq[0] += wv.x * wv.x;
            ssum[1] += wv.y; ssq[1] += wv.y * wv.y;
            ssum[2] += wv.z; ssq[2] += wv.z * wv.z;
            ssum[3] += wv.w; ssq[3] += wv.w * wv.w;
        }
    }
    sbuf[t] = 0.f;
    __syncthreads();
    if (g < 2) {
        int f = u * 8 + g * 4;
#pragma unroll
        for (int j = 0; j < 4; j++) {
            atomicAdd(&sbuf[f + j], ssum[j]);
            atomicAdd(&sbuf[128 + f + j], ssq[j]);
        }
    }
    __syncthreads();
    atomicAdd(&stats[t], sbuf[t]);
}

// ---------------- pooling: one block per graph (batch sorted), atomic-free ----------------
__global__ __launch_bounds__(256) void pool2_kernel(const float* __restrict__ h,
                                                    const float* __restrict__ stats_in,
                                                    const float* __restrict__ bn_sc,
                                                    const float* __restrict__ bn_bi,
                                                    const int* __restrict__ batch,
                                                    float* __restrict__ pooled) {
    int g = blockIdx.x;  // 0..GG-1
    int t = threadIdx.x;
    int f = t & 127, half = t >> 7;
    float mean = stats_in[f] * (1.0f / N_NODES);
    float var = fmaxf(stats_in[128 + f] * (1.0f / N_NODES) - mean * mean, 0.f);
    float ga = bn_sc[f] * rsqrtf(var + EPSV);
    float gb = bn_bi[f] - mean * ga;
    // node range [lo,hi) for graph g via binary search (uniform across threads)
    int lo, hi;
    {
        int a = 0, b = N_NODES;
        while (a < b) { int m = (a + b) >> 1; if (batch[m] < g) a = m + 1; else b = m; }
        lo = a;
        b = N_NODES;
        while (a < b) { int m = (a + b) >> 1; if (batch[m] < g + 1) a = m + 1; else b = m; }
        hi = a;
    }
    float acc = 0.f;
    for (int i = lo + half; i < hi; i += 2)
        acc += fmaxf(h[(size_t)i * 128 + f] * ga + gb, 0.f);
    __shared__ float sb[256];
    sb[t] = acc;
    __syncthreads();
    if (t < 128)
        pooled[(size_t)g * 128 + t] = (sb[t] + sb[t + 128]) / fmaxf((float)(hi - lo), 1.0f);
}

// ---------------- output head: post-BN affine computed inline from stats5 ----------------
__global__ void out2_kernel(const float* __restrict__ Z, const float* __restrict__ stats5,
                            const float* __restrict__ bn_sc, const float* __restrict__ bn_bi,
                            const float* __restrict__ outW, const float* __restrict__ outb,
                            float* __restrict__ out) {
    int g = blockIdx.x;
    int lane = threadIdx.x;  // 64
    int d0 = lane * 2;
    const float invN = 1.0f / GG;
    float m0 = stats5[d0] * invN, m1 = stats5[d0 + 1] * invN;
    float v0 = fmaxf(stats5[128 + d0] * invN - m0 * m0, 0.f);
    float v1 = fmaxf(stats5[128 + d0 + 1] * invN - m1 * m1, 0.f);
    float ga0 = bn_sc[d0] * rsqrtf(v0 + EPSV), gb0 = bn_bi[d0] - m0 * ga0;
    float ga1 = bn_sc[d0 + 1] * rsqrtf(v1 + EPSV), gb1 = bn_bi[d0 + 1] - m1 * ga1;
    float2 z = *(const float2*)&Z[(size_t)g * 128 + d0];
    float s = fmaxf(z.x * ga0 + gb0, 0.f) * outW[d0] +
              fmaxf(z.y * ga1 + gb1, 0.f) * outW[d0 + 1];
    for (int off = 32; off; off >>= 1) s += __shfl_down(s, off);
    if (lane == 0) out[g] = s + outb[0];
}

// ---------------- host ----------------
extern "C" void kernel_launch(void* const* d_in, const int* in_sizes, int n_in,
                              void* d_out, int out_size, void* d_ws, size_t ws_size,
                              hipStream_t stream) {
    const float* x         = (const float*)d_in[0];
    const int*   ei        = (const int*)d_in[1];
    const float* ew        = (const float*)d_in[2];
    const int*   batch     = (const int*)d_in[3];
    const float* pre_W     = (const float*)d_in[4];
    const float* pre_b     = (const float*)d_in[5];
    const float* pre_bn_s  = (const float*)d_in[6];
    const float* pre_bn_b  = (const float*)d_in[7];
    const float* convW     = (const float*)d_in[8];
    const float* convb     = (const float*)d_in[9];
    const float* bn_s      = (const float*)d_in[10];
    const float* bn_b      = (const float*)d_in[11];
    const float* post_W    = (const float*)d_in[12];
    const float* post_b    = (const float*)d_in[13];
    const float* post_bn_s = (const float*)d_in[14];
    const float* post_bn_b = (const float*)d_in[15];
    const float* out_W     = (const float*)d_in[16];
    const float* out_b     = (const float*)d_in[17];

    float* ws = (float*)d_ws;
    float* cd     = ws;                        // 2N (counts/deg interleaved, zeroed)
    float* stats  = ws + 2 * N_NODES;          // 6*256 (zeroed)
    size_t zero_floats = 2 * N_NODES + 6 * 256;
    float* pooled = stats + 6 * 256;           // 256*128 (fully written by pool2)
    float* Z      = pooled + GG * 128;         // 256*128 (fully written by gemm128)
    int*   rowptr = (int*)(Z + GG * 128);      // N+1
    int*   cursor = rowptr + N_NODES + 1;      // N
    int*   bsums  = cursor + N_NODES;          // NB
    int*   boffs  = bsums + NB;                // NB
    size_t woff = (size_t)((float*)(boffs + NB) - ws);
    woff = (woff + 3) & ~(size_t)3;            // 16B align for uint4
    unsigned short* Wf = (unsigned short*)(ws + woff);  // 5*16384 ushort
    size_t eoff = woff + 40960;
    eoff = (eoff + 1) & ~(size_t)1;            // 8B align
    uint2* edat   = (uint2*)(ws + eoff);       // E uint2
    float* dinv   = ws + eoff + 2 * (size_t)N_EDGES;  // N
    size_t off = eoff + 2 * (size_t)N_EDGES + N_NODES;
    off = (off + 3) & ~(size_t)3;
    float* hA = ws + off;                                    // N*128 fp32
    unsigned* hB = (unsigned*)(hA + (size_t)N_NODES * 128);  // N*64 packed bf16 (16B-aligned)

    hipMemsetAsync(d_ws, 0, zero_floats * sizeof(float), stream);
    wprep_kernel<<<320, 256, 0, stream>>>(pre_W, convW, Wf);
    count_deg_kernel<<<(N_EDGES + 255) / 256, 256, 0, stream>>>(ei, ew, cd);
    blocksum_kernel<<<NB, 256, 0, stream>>>(cd, bsums);
    scan_bsums_kernel<<<1, 256, 0, stream>>>(bsums, boffs, rowptr);
    rowptr_kernel<<<NB, 256, 0, stream>>>(cd, boffs, rowptr, cursor, dinv);
    fill_kernel<<<(N_EDGES + 255) / 256, 256, 0, stream>>>(ei, ew, dinv, cursor, edat);

    // pre FC: hA = x @ pre_W + pre_b (MFMA bf16), stats0
    gemm_mfma<false, true, false><<<GEMM_BLOCKS, 256, 0, stream>>>(
        x, N_NODES, (const uint4*)Wf, nullptr, nullptr, nullptr, pre_b, hA, stats + 0);
    for (int l = 0; l < LL; l++) {
        const float* sc = (l == 0) ? pre_bn_s : bn_s + (l - 1) * 128;
        const float* bi = (l == 0) ? pre_bn_b : bn_b + (l - 1) * 128;
        // hB = bf16(relu(bn(hA)) @ convW[l]) row-major
        gemm_mfma<true, false, true><<<GEMM_BLOCKS, 256, 0, stream>>>(
            hA, N_NODES, (const uint4*)(Wf + (size_t)(1 + l) * 16384), stats + l * 256, sc, bi,
            nullptr, hB, nullptr);
        // hA = scatter(hB) + convb[l], stats_{l+1}
        aggv_kernel<<<AGG_BLOCKS, 256, 0, stream>>>(hB, rowptr, edat, dinv, convb + l * 128, hA,
                                                    stats + (l + 1) * 256);
    }
    // mean pool of relu(bn(hA)): one block per graph, atomic-free, divides inline
    pool2_kernel<<<GG, 256, 0, stream>>>(hA, stats + 4 * 256, bn_s + 3 * 128, bn_b + 3 * 128,
                                         batch, pooled);
    // post FC (fp32, tiny) + stats5
    dim3 gP(2, 4);
    gemm128<true, true><<<gP, 256, 0, stream>>>(pooled, GG, post_W, post_b, Z, stats + 5 * 256);
    // out head with inline post-BN affine
    out2_kernel<<<GG, 64, 0, stream>>>(Z, stats + 5 * 256, post_bn_s, post_bn_b, out_W, out_b,
                                       (float*)d_out);
}

// Round 10
// 660.198 us; speedup vs baseline: 1.0764x; 1.0453x over previous
//
#include <hip/hip_runtime.h>

#define N_NODES 50000
#define N_EDGES 800000
#define DD 128
#define GG 256
#define LL 4
#define EPSV 1e-5f
#define NB 196  // ceil(N_NODES/256)
#define AGG_BLOCKS 1024   // 4096 waves x 13-node contiguous chunks
#define AGG_CHUNK 13      // 4096*13 = 53248 >= 50000
#define GEMM_BLOCKS 782   // ceil(N/64)
#define WSCALE 268435456.0f  // 2^28 fixed-point for packed degree weight

typedef __attribute__((ext_vector_type(8))) short s16x8;    // 8 bf16 (4 VGPRs)
typedef __attribute__((ext_vector_type(4))) float f32x4;    // 4 fp32 acc

// ---------------- bf16 helpers ----------------
static __device__ __forceinline__ unsigned bf16pack(float a, float b) {
    unsigned ua = __float_as_uint(a), ub = __float_as_uint(b);
    ua = (ua + 0x7FFFu + ((ua >> 16) & 1u)) >> 16;  // RNE
    ub = (ub + 0x7FFFu + ((ub >> 16) & 1u)) >> 16;
    return ua | (ub << 16);
}
static __device__ __forceinline__ unsigned short bf16r(float a) {
    unsigned u = __float_as_uint(a);
    u = (u + 0x7FFFu + ((u >> 16) & 1u)) >> 16;
    return (unsigned short)u;
}
static __device__ __forceinline__ float2 bf16unpack(unsigned u) {
    float2 r;
    r.x = __uint_as_float(u << 16);
    r.y = __uint_as_float(u & 0xFFFF0000u);
    return r;
}

// ---------------- setup kernels ----------------

// one u64 atomic per edge: count in bits [40..63], fixed-point(2^28) weight sum in [0..39]
__global__ void count_deg_kernel(const int* __restrict__ ei, const float* __restrict__ w,
                                 unsigned long long* __restrict__ cd64) {
    int e = blockIdx.x * 256 + threadIdx.x;
    if (e < N_EDGES) {
        int d = ei[N_EDGES + e];
        unsigned long long pack =
            (1ull << 40) | (unsigned long long)(w[e] * WSCALE);
        atomicAdd(&cd64[d], pack);
    }
}

__global__ __launch_bounds__(256) void blocksum_kernel(const unsigned long long* __restrict__ cd64,
                                                       int* __restrict__ bsums) {
    int i = blockIdx.x * 256 + threadIdx.x;
    int v = (i < N_NODES) ? (int)(cd64[i] >> 40) : 0;
    for (int off = 32; off; off >>= 1) v += __shfl_down(v, off);
    __shared__ int s[4];
    if ((threadIdx.x & 63) == 0) s[threadIdx.x >> 6] = v;
    __syncthreads();
    if (threadIdx.x == 0) bsums[blockIdx.x] = s[0] + s[1] + s[2] + s[3];
}

__global__ __launch_bounds__(256) void scan_bsums_kernel(const int* __restrict__ bsums,
                                                         int* __restrict__ boffs,
                                                         int* __restrict__ rowptr) {
    __shared__ int s[256];
    int t = threadIdx.x;
    int v = (t < NB) ? bsums[t] : 0;
    s[t] = v;
    __syncthreads();
    for (int off = 1; off < 256; off <<= 1) {
        int u = (t >= off) ? s[t - off] : 0;
        __syncthreads();
        s[t] += u;
        __syncthreads();
    }
    if (t < NB) boffs[t] = s[t] - v;  // exclusive
    if (t == 0) rowptr[N_NODES] = N_EDGES;
}

// per-block scan + block offset -> rowptr/cursor; dinv decoded from packed cd64
__global__ __launch_bounds__(256) void rowptr_kernel(const unsigned long long* __restrict__ cd64,
                                                     const int* __restrict__ boffs,
                                                     int* __restrict__ rowptr,
                                                     int* __restrict__ cursor,
                                                     float* __restrict__ dinv) {
    __shared__ int s[256];
    int i = blockIdx.x * 256 + threadIdx.x;
    int t = threadIdx.x;
    unsigned long long v64 = (i < N_NODES) ? cd64[i] : 0ull;
    int c = (int)(v64 >> 40);
    s[t] = c;
    __syncthreads();
    for (int off = 1; off < 256; off <<= 1) {
        int u = (t >= off) ? s[t - off] : 0;
        __syncthreads();
        s[t] += u;
        __syncthreads();
    }
    if (i < N_NODES) {
        int r = boffs[blockIdx.x] + s[t] - c;
        rowptr[i] = r;
        cursor[i] = r;
        float wsum = (float)(v64 & ((1ull << 40) - 1)) * (1.0f / WSCALE);
        dinv[i] = rsqrtf(fmaxf(wsum + 2.0f, EPSV));  // self-loop weight 2.0
    }
}

// edat stores raw (src, w); dinv folded into h' scaling (gemm epilogue) + agg final mult
__global__ void fill_kernel(const int* __restrict__ ei, const float* __restrict__ w,
                            int* __restrict__ cursor, uint2* __restrict__ edat) {
    int e = blockIdx.x * 256 + threadIdx.x;
    if (e < N_EDGES) {
        int s_ = ei[e];
        int d = ei[N_EDGES + e];
        int pos = atomicAdd(&cursor[d], 1);
        edat[pos] = make_uint2((unsigned)s_, __float_as_uint(w[e]));
    }
}

// ---------------- weight prep: fp32 W[k][n] -> fragment-ordered bf16 ----------------
__global__ void wprep_kernel(const float* __restrict__ preW, const float* __restrict__ convW,
                             unsigned short* __restrict__ Wf) {
    int idx = blockIdx.x * 256 + threadIdx.x;  // 5*16384
    if (idx >= 5 * 16384) return;
    int l = idx >> 14, kn = idx & 16383;
    int k = kn >> 7, nn = kn & 127;
    float v = (l == 0) ? preW[kn] : convW[(l - 1) * 16384 + kn];
    int nt = nn >> 4, nl = nn & 15, kc = k >> 5, q = (k >> 3) & 3, j = k & 7;
    Wf[(size_t)l * 16384 + ((((nt * 4 + kc) * 4 + q) * 16 + nl) * 8 + j)] = bf16r(v);
}

// ---------------- MFMA GEMM: out[n,128] = act(A)[n,128] @ W[128,128] ----------------
// OUTBF16 writes row-major packed bf16 pairs scaled by dinv[row] (h' = dinv*h).
template <bool AFFINE, bool STATS, bool OUTBF16>
__global__ __launch_bounds__(256) void gemm_mfma(const float* __restrict__ A, int n,
                                                 const uint4* __restrict__ Wf,
                                                 const float* __restrict__ stats_in,
                                                 const float* __restrict__ bn_sc,
                                                 const float* __restrict__ bn_bi,
                                                 const float* __restrict__ bias,
                                                 const float* __restrict__ dinv,
                                                 void* __restrict__ outv,
                                                 float* __restrict__ stats_out) {
    __shared__ unsigned short Af[8192];  // A frags
    __shared__ float WC[8448];           // W frags then C tile 64x132
    __shared__ float affg[128], affb[128];
    int t = threadIdx.x;
    int row0 = blockIdx.x * 64;

    if (AFFINE) {
        if (t < 128) {
            float mean = stats_in[t] * (1.0f / N_NODES);
            float var = fmaxf(stats_in[128 + t] * (1.0f / N_NODES) - mean * mean, 0.f);
            float g = bn_sc[t] * rsqrtf(var + EPSV);
            affg[t] = g;
            affb[t] = bn_bi[t] - mean * g;
        }
        __syncthreads();
    }
    {  // stage W fragments
        uint4* Wl = (uint4*)WC;
#pragma unroll
        for (int it = 0; it < 8; ++it) Wl[t + it * 256] = Wf[t + it * 256];
    }
    {  // stage A into fragment order (bf16), affine+relu fused
#pragma unroll
        for (int it = 0; it < 8; ++it) {
            int f = t * 4 + it * 1024;
            int r = f >> 7, c = f & 127;
            int row = row0 + r;
            float4 v = make_float4(0.f, 0.f, 0.f, 0.f);
            if (row < n) v = *(const float4*)&A[(size_t)row * 128 + c];
            if (AFFINE) {
                float4 g = *(float4*)&affg[c];
                float4 bb = *(float4*)&affb[c];
                v.x = fmaxf(v.x * g.x + bb.x, 0.f);
                v.y = fmaxf(v.y * g.y + bb.y, 0.f);
                v.z = fmaxf(v.z * g.z + bb.z, 0.f);
                v.w = fmaxf(v.w * g.w + bb.w, 0.f);
            }
            int w = r >> 4, mrow = r & 15, kc = c >> 5, q = (c >> 3) & 3, jo = c & 7;
            unsigned short* dst = &Af[(((w * 4 + kc) * 4 + q) * 16 + mrow) * 8 + jo];
            *(uint2*)dst = make_uint2(bf16pack(v.x, v.y), bf16pack(v.z, v.w));
        }
    }
    __syncthreads();

    int wv = t >> 6, lane = t & 63, q = lane >> 4, ml = lane & 15;
    f32x4 acc[8];
#pragma unroll
    for (int nt = 0; nt < 8; nt++) acc[nt] = (f32x4){0.f, 0.f, 0.f, 0.f};
    const unsigned short* Wb = (const unsigned short*)WC;
#pragma unroll
    for (int kc = 0; kc < 4; kc++) {
        s16x8 a = *(const s16x8*)&Af[(((wv * 4 + kc) * 4 + q) * 16 + ml) * 8];
#pragma unroll
        for (int nt = 0; nt < 8; nt++) {
            s16x8 b = *(const s16x8*)&Wb[(((nt * 4 + kc) * 4 + q) * 16 + ml) * 8];
            acc[nt] = __builtin_amdgcn_mfma_f32_16x16x32_bf16(a, b, acc[nt], 0, 0, 0);
        }
    }
    __syncthreads();  // all W-frag reads done; reuse WC as C tile
    float* Cs = WC;   // [64][132]
#pragma unroll
    for (int nt = 0; nt < 8; nt++)
#pragma unroll
        for (int rr = 0; rr < 4; rr++)
            Cs[(wv * 16 + q * 4 + rr) * 132 + nt * 16 + ml] = acc[nt][rr];
    __syncthreads();

    float csum[4] = {0, 0, 0, 0}, csq[4] = {0, 0, 0, 0};
#pragma unroll
    for (int it = 0; it < 8; ++it) {
        int f = t * 4 + it * 1024;
        int r = f >> 7, c = f & 127;
        int row = row0 + r;
        if (row < n) {
            float4 v = *(float4*)&Cs[r * 132 + c];
            if (!AFFINE) {
                v.x += bias[c];
                v.y += bias[c + 1];
                v.z += bias[c + 2];
                v.w += bias[c + 3];
            }
            if (OUTBF16) {
                float dv = dinv[row];  // h' = dinv*h (folds edge norm out of fill)
                uint2 p;
                p.x = bf16pack(v.x * dv, v.y * dv);
                p.y = bf16pack(v.z * dv, v.w * dv);
                *(uint2*)&((unsigned*)outv)[(size_t)row * 64 + (c >> 1)] = p;
            } else {
                *(float4*)&((float*)outv)[(size_t)row * 128 + c] = v;
            }
            if (STATS) {
                csum[0] += v.x; csq[0] += v.x * v.x;
                csum[1] += v.y; csq[1] += v.y * v.y;
                csum[2] += v.z; csq[2] += v.z * v.z;
                csum[3] += v.w; csq[3] += v.w * v.w;
            }
        }
    }
    if (STATS) {
        __syncthreads();
        if (t < 128) { affg[t] = 0.f; affb[t] = 0.f; }
        __syncthreads();
        int c = (t & 31) * 4;
#pragma unroll
        for (int j = 0; j < 4; j++) {
            atomicAdd(&affg[c + j], csum[j]);
            atomicAdd(&affb[c + j], csq[j]);
        }
        __syncthreads();
        if (t < 128) {
            atomicAdd(&stats_out[t], affg[t]);
            atomicAdd(&stats_out[128 + t], affb[t]);
        }
    }
}

// ---------------- fp32 GEMM (post FC only: 256 rows) ----------------
template <bool STATS, bool BIAS>
__global__ __launch_bounds__(256) void gemm128(const float* __restrict__ A, int n,
                                               const float* __restrict__ W,
                                               const float* __restrict__ bias,
                                               float* __restrict__ out,
                                               float* __restrict__ stats) {
    __shared__ float As[128][64];
    __shared__ float Ws[128][64];
    int tid = threadIdx.x;
    int row0 = blockIdx.y * 64;
    int col0 = blockIdx.x * 64;
    {
        int rsub = tid >> 5;
        int k4 = (tid & 31) * 4;
        for (int it = 0; it < 8; ++it) {
            int r = it * 8 + rsub;
            int row = row0 + r;
            float4 v = make_float4(0.f, 0.f, 0.f, 0.f);
            if (row < n) v = *(const float4*)&A[(size_t)row * 128 + k4];
            As[k4 + 0][r] = v.x;
            As[k4 + 1][r] = v.y;
            As[k4 + 2][r] = v.z;
            As[k4 + 3][r] = v.w;
        }
    }
    {
        int krow = tid >> 4;
        int c4 = (tid & 15) * 4;
        for (int it = 0; it < 8; ++it) {
            int k = it * 16 + krow;
            *(float4*)&Ws[k][c4] = *(const float4*)&W[k * 128 + col0 + c4];
        }
    }
    __syncthreads();
    int ty = tid >> 4, tx = tid & 15;
    float acc[4][4];
#pragma unroll
    for (int i = 0; i < 4; i++)
#pragma unroll
        for (int j = 0; j < 4; j++) acc[i][j] = 0.f;
#pragma unroll 4
    for (int k = 0; k < 128; k++) {
        float4 a = *(const float4*)&As[k][ty * 4];
        float4 b = *(const float4*)&Ws[k][tx * 4];
        float av[4] = {a.x, a.y, a.z, a.w};
        float bv[4] = {b.x, b.y, b.z, b.w};
#pragma unroll
        for (int i = 0; i < 4; i++)
#pragma unroll
            for (int j = 0; j < 4; j++) acc[i][j] += av[i] * bv[j];
    }
    float csum[4] = {0, 0, 0, 0}, csq[4] = {0, 0, 0, 0};
#pragma unroll
    for (int i = 0; i < 4; i++) {
        int row = row0 + ty * 4 + i;
        if (row < n) {
#pragma unroll
            for (int j = 0; j < 4; j++) {
                float v = acc[i][j];
                if (BIAS) v += bias[col0 + tx * 4 + j];
                out[(size_t)row * 128 + col0 + tx * 4 + j] = v;
                if (STATS) { csum[j] += v; csq[j] += v * v; }
            }
        }
    }
    if (STATS) {
        float* ps = &As[0][0];
        float* pq = &As[0][0] + 64;
        __syncthreads();
        if (tid < 64) { ps[tid] = 0.f; pq[tid] = 0.f; }
        __syncthreads();
#pragma unroll
        for (int j = 0; j < 4; j++) {
            atomicAdd(&ps[tx * 4 + j], csum[j]);
            atomicAdd(&pq[tx * 4 + j], csq[j]);
        }
        __syncthreads();
        if (tid < 64) {
            atomicAdd(&stats[col0 + tid], ps[tid]);
            atomicAdd(&stats[128 + col0 + tid], pq[tid]);
        }
    }
}

// ---------------- aggregation: wide-gather on h' = dinv*h ------------------------------
// out[i] = dinv[i]*( sum_e w_e*h'[src] + 2*h'[i] ) + bias
__global__ __launch_bounds__(256) void aggv_kernel(const unsigned* __restrict__ hT,
                                                   const int* __restrict__ rowptr,
                                                   const uint2* __restrict__ edat,
                                                   const float* __restrict__ dinv,
                                                   const float* __restrict__ convb,
                                                   float* __restrict__ out,
                                                   float* __restrict__ stats) {
    __shared__ float sbuf[256];
    int t = threadIdx.x;
    int wave = t >> 6, lane = t & 63;
    int g = lane >> 4, u = lane & 15;
    int wid = blockIdx.x * 4 + wave;
    int i0 = wid * AGG_CHUNK;
    int i1 = min(i0 + AGG_CHUNK, N_NODES);
    float4 bb0 = *(const float4*)&convb[u * 8];
    float4 bb1 = *(const float4*)&convb[u * 8 + 4];
    float ssum[4] = {0, 0, 0, 0}, ssq[4] = {0, 0, 0, 0};
    for (int i = i0; i < i1; ++i) {
        float acc[8];
#pragma unroll
        for (int k = 0; k < 8; k++) acc[k] = 0.f;
        int e = rowptr[i], end = rowptr[i + 1];
        for (int eb = e; eb < end; eb += 4) {
            int ee = eb + g;
            uint2 ed = (ee < end) ? edat[ee] : make_uint2(0u, 0u);
            float nrm = __uint_as_float(ed.y);
            uint4 hv = *(const uint4*)&hT[(size_t)ed.x * 64 + u * 4];
            float2 p0 = bf16unpack(hv.x), p1 = bf16unpack(hv.y);
            float2 p2 = bf16unpack(hv.z), p3 = bf16unpack(hv.w);
            acc[0] += nrm * p0.x; acc[1] += nrm * p0.y;
            acc[2] += nrm * p1.x; acc[3] += nrm * p1.y;
            acc[4] += nrm * p2.x; acc[5] += nrm * p2.y;
            acc[6] += nrm * p3.x; acc[7] += nrm * p3.y;
        }
#pragma unroll
        for (int k = 0; k < 8; k++) {
            acc[k] += __shfl_xor(acc[k], 16);
            acc[k] += __shfl_xor(acc[k], 32);
        }
        // self loop: + 2*h'[i] (h' already dinv-scaled)
        {
            uint4 hs = *(const uint4*)&hT[(size_t)i * 64 + u * 4];
            float2 p0 = bf16unpack(hs.x), p1 = bf16unpack(hs.y);
            float2 p2 = bf16unpack(hs.z), p3 = bf16unpack(hs.w);
            acc[0] += 2.f * p0.x; acc[1] += 2.f * p0.y;
            acc[2] += 2.f * p1.x; acc[3] += 2.f * p1.y;
            acc[4] += 2.f * p2.x; acc[5] += 2.f * p2.y;
            acc[6] += 2.f * p3.x; acc[7] += 2.f * p3.y;
        }
        float di = dinv[i];
        if (g < 2) {
            float4 wv;
            if (g == 0)
                wv = make_float4(di * acc[0] + bb0.x, di * acc[1] + bb0.y,
                                 di * acc[2] + bb0.z, di * acc[3] + bb0.w);
            else
                wv = make_float4(di * acc[4] + bb1.x, di * acc[5] + bb1.y,
                                 di * acc[6] + bb1.z, di * acc[7] + bb1.w);
            *(float4*)&out[(size_t)i * 128 + u * 8 + g * 4] = wv;
            ssum[0] += wv.x; ssq[0] += wv.x * wv.x;
            ssum[1] += wv.y; ssq[1] += wv.y * wv.y;
            ssum[2] += wv.z; ssq[2] += wv.z * wv.z;
            ssum[3] += wv.w; ssq[3] += wv.w * wv.w;
        }
    }
    sbuf[t] = 0.f;
    __syncthreads();
    if (g < 2) {
        int f = u * 8 + g * 4;
#pragma unroll
        for (int j = 0; j < 4; j++) {
            atomicAdd(&sbuf[f + j], ssum[j]);
            atomicAdd(&sbuf[128 + f + j], ssq[j]);
        }
    }
    __syncthreads();
    atomicAdd(&stats[t], sbuf[t]);
}

// ---------------- pooling: one block per graph (batch sorted), atomic-free ----------------
__global__ __launch_bounds__(256) void pool2_kernel(const float* __restrict__ h,
                                                    const float* __restrict__ stats_in,
                                                    const float* __restrict__ bn_sc,
                                                    const float* __restrict__ bn_bi,
                                                    const int* __restrict__ batch,
                                                    float* __restrict__ pooled) {
    int g = blockIdx.x;  // 0..GG-1
    int t = threadIdx.x;
    int f = t & 127, half = t >> 7;
    float mean = stats_in[f] * (1.0f / N_NODES);
    float var = fmaxf(stats_in[128 + f] * (1.0f / N_NODES) - mean * mean, 0.f);
    float ga = bn_sc[f] * rsqrtf(var + EPSV);
    float gb = bn_bi[f] - mean * ga;
    int lo, hi;
    {
        int a = 0, b = N_NODES;
        while (a < b) { int m = (a + b) >> 1; if (batch[m] < g) a = m + 1; else b = m; }
        lo = a;
        b = N_NODES;
        while (a < b) { int m = (a + b) >> 1; if (batch[m] < g + 1) a = m + 1; else b = m; }
        hi = a;
    }
    float acc = 0.f;
    for (int i = lo + half; i < hi; i += 2)
        acc += fmaxf(h[(size_t)i * 128 + f] * ga + gb, 0.f);
    __shared__ float sb[256];
    sb[t] = acc;
    __syncthreads();
    if (t < 128)
        pooled[(size_t)g * 128 + t] = (sb[t] + sb[t + 128]) / fmaxf((float)(hi - lo), 1.0f);
}

// ---------------- output head: post-BN affine computed inline from stats5 ----------------
__global__ void out2_kernel(const float* __restrict__ Z, const float* __restrict__ stats5,
                            const float* __restrict__ bn_sc, const float* __restrict__ bn_bi,
                            const float* __restrict__ outW, const float* __restrict__ outb,
                            float* __restrict__ out) {
    int g = blockIdx.x;
    int lane = threadIdx.x;  // 64
    int d0 = lane * 2;
    const float invN = 1.0f / GG;
    float m0 = stats5[d0] * invN, m1 = stats5[d0 + 1] * invN;
    float v0 = fmaxf(stats5[128 + d0] * invN - m0 * m0, 0.f);
    float v1 = fmaxf(stats5[128 + d0 + 1] * invN - m1 * m1, 0.f);
    float ga0 = bn_sc[d0] * rsqrtf(v0 + EPSV), gb0 = bn_bi[d0] - m0 * ga0;
    float ga1 = bn_sc[d0 + 1] * rsqrtf(v1 + EPSV), gb1 = bn_bi[d0 + 1] - m1 * ga1;
    float2 z = *(const float2*)&Z[(size_t)g * 128 + d0];
    float s = fmaxf(z.x * ga0 + gb0, 0.f) * outW[d0] +
              fmaxf(z.y * ga1 + gb1, 0.f) * outW[d0 + 1];
    for (int off = 32; off; off >>= 1) s += __shfl_down(s, off);
    if (lane == 0) out[g] = s + outb[0];
}

// ---------------- host ----------------
extern "C" void kernel_launch(void* const* d_in, const int* in_sizes, int n_in,
                              void* d_out, int out_size, void* d_ws, size_t ws_size,
                              hipStream_t stream) {
    const float* x         = (const float*)d_in[0];
    const int*   ei        = (const int*)d_in[1];
    const float* ew        = (const float*)d_in[2];
    const int*   batch     = (const int*)d_in[3];
    const float* pre_W     = (const float*)d_in[4];
    const float* pre_b     = (const float*)d_in[5];
    const float* pre_bn_s  = (const float*)d_in[6];
    const float* pre_bn_b  = (const float*)d_in[7];
    const float* convW     = (const float*)d_in[8];
    const float* convb     = (const float*)d_in[9];
    const float* bn_s      = (const float*)d_in[10];
    const float* bn_b      = (const float*)d_in[11];
    const float* post_W    = (const float*)d_in[12];
    const float* post_b    = (const float*)d_in[13];
    const float* post_bn_s = (const float*)d_in[14];
    const float* post_bn_b = (const float*)d_in[15];
    const float* out_W     = (const float*)d_in[16];
    const float* out_b     = (const float*)d_in[17];

    float* ws = (float*)d_ws;
    unsigned long long* cd64 = (unsigned long long*)ws;  // N u64 = 2N floats (zeroed)
    float* stats  = ws + 2 * N_NODES;          // 6*256 (zeroed)
    size_t zero_floats = 2 * N_NODES + 6 * 256;
    float* pooled = stats + 6 * 256;           // 256*128 (fully written by pool2)
    float* Z      = pooled + GG * 128;         // 256*128 (fully written by gemm128)
    int*   rowptr = (int*)(Z + GG * 128);      // N+1
    int*   cursor = rowptr + N_NODES + 1;      // N
    int*   bsums  = cursor + N_NODES;          // NB
    int*   boffs  = bsums + NB;                // NB
    size_t woff = (size_t)((float*)(boffs + NB) - ws);
    woff = (woff + 3) & ~(size_t)3;            // 16B align for uint4
    unsigned short* Wf = (unsigned short*)(ws + woff);  // 5*16384 ushort
    size_t eoff = woff + 40960;
    eoff = (eoff + 1) & ~(size_t)1;            // 8B align
    uint2* edat   = (uint2*)(ws + eoff);       // E uint2
    float* dinv   = ws + eoff + 2 * (size_t)N_EDGES;  // N
    size_t off = eoff + 2 * (size_t)N_EDGES + N_NODES;
    off = (off + 3) & ~(size_t)3;
    float* hA = ws + off;                                    // N*128 fp32
    unsigned* hB = (unsigned*)(hA + (size_t)N_NODES * 128);  // N*64 packed bf16 (16B-aligned)

    hipMemsetAsync(d_ws, 0, zero_floats * sizeof(float), stream);
    wprep_kernel<<<320, 256, 0, stream>>>(pre_W, convW, Wf);
    count_deg_kernel<<<(N_EDGES + 255) / 256, 256, 0, stream>>>(ei, ew, cd64);
    blocksum_kernel<<<NB, 256, 0, stream>>>(cd64, bsums);
    scan_bsums_kernel<<<1, 256, 0, stream>>>(bsums, boffs, rowptr);
    rowptr_kernel<<<NB, 256, 0, stream>>>(cd64, boffs, rowptr, cursor, dinv);
    fill_kernel<<<(N_EDGES + 255) / 256, 256, 0, stream>>>(ei, ew, cursor, edat);

    // pre FC: hA = x @ pre_W + pre_b (MFMA bf16), stats0
    gemm_mfma<false, true, false><<<GEMM_BLOCKS, 256, 0, stream>>>(
        x, N_NODES, (const uint4*)Wf, nullptr, nullptr, nullptr, pre_b, nullptr, hA, stats + 0);
    for (int l = 0; l < LL; l++) {
        const float* sc = (l == 0) ? pre_bn_s : bn_s + (l - 1) * 128;
        const float* bi = (l == 0) ? pre_bn_b : bn_b + (l - 1) * 128;
        // hB = bf16(dinv[row] * (relu(bn(hA)) @ convW[l]))  (h' = dinv*h)
        gemm_mfma<true, false, true><<<GEMM_BLOCKS, 256, 0, stream>>>(
            hA, N_NODES, (const uint4*)(Wf + (size_t)(1 + l) * 16384), stats + l * 256, sc, bi,
            nullptr, dinv, hB, nullptr);
        // hA = dinv[i]*(gather(hB) + 2*h'[i]) + convb[l], stats_{l+1}
        aggv_kernel<<<AGG_BLOCKS, 256, 0, stream>>>(hB, rowptr, edat, dinv, convb + l * 128, hA,
                                                    stats + (l + 1) * 256);
    }
    // mean pool of relu(bn(hA)): one block per graph, atomic-free, divides inline
    pool2_kernel<<<GG, 256, 0, stream>>>(hA, stats + 4 * 256, bn_s + 3 * 128, bn_b + 3 * 128,
                                         batch, pooled);
    // post FC (fp32, tiny) + stats5
    dim3 gP(2, 4);
    gemm128<true, true><<<gP, 256, 0, stream>>>(pooled, GG, post_W, post_b, Z, stats + 5 * 256);
    // out head with inline post-BN affine
    out2_kernel<<<GG, 64, 0, stream>>>(Z, stats + 5 * 256, post_bn_s, post_bn_b, out_W, out_b,
                                       (float*)d_out);
}